// Round 1
// baseline (2357.014 us; speedup 1.0000x reference)
//
#include <hip/hip_runtime.h>
#include <math.h>

#define B_SZ 16
#define L_SZ 1024
#define NMAT (B_SZ * L_SZ)   // 16384
#define DIMV 136
#define QKVD 408
#define HD 34
#define NH 4
#define NSWEEP 8
#define MAT_STRIDE 260       // per-matrix LDS stride (256 + 4 pad to spread banks)

// ---------------------------------------------------------------------------
// Parallel cyclic Jacobi eigensolver for one 16x16 symmetric matrix per
// 16-lane group. Own column lives in registers (a[16]); LDS mirror (Acol)
// provides partner-column access and scalar picks (runtime indices OK in
// LDS). V accumulated identically (column-mix only). Round-robin pairing:
// round r pairs (r,15) and ((r+k)%15,(r-k)%15) k=1..7 -- all disjoint.
// Loops over r and k are fully unrolled so register indices are static.
// ---------------------------------------------------------------------------
__device__ __forceinline__ void jacobi16(float* __restrict__ Acol, float* __restrict__ Vcol,
                                         float2* __restrict__ cs, float a[16], float v[16],
                                         const int sub) {
  __syncthreads();  // LDS init visible
  for (int sweep = 0; sweep < NSWEEP; ++sweep) {
#pragma unroll
    for (int r = 0; r < 15; ++r) {
      // ---- pairing (r is compile-time; sub is a runtime value, not an index) ----
      int partner;
      if (sub == 15) partner = r;
      else {
        int d = sub - r; if (d < 0) d += 15;
        if (d == 0) partner = 15;
        else if (d <= 7) { partner = r - d; if (partner < 0) partner += 15; }
        else { partner = r + 15 - d; if (partner >= 15) partner -= 15; }
      }
      const bool amP = (sub < partner);
      const int p_ = amP ? sub : partner;
      const int q_ = amP ? partner : sub;

      // ---- read pivot scalars + partner columns from LDS (current state) ----
      const float app = Acol[p_ * 16 + p_];
      const float aqq = Acol[q_ * 16 + q_];
      const float apq = Acol[p_ * 16 + q_];
      float oa[16], ov[16];
#pragma unroll
      for (int i4 = 0; i4 < 4; ++i4) {
        float4 t0 = *(const float4*)&Acol[partner * 16 + i4 * 4];
        oa[i4*4+0]=t0.x; oa[i4*4+1]=t0.y; oa[i4*4+2]=t0.z; oa[i4*4+3]=t0.w;
        float4 t1 = *(const float4*)&Vcol[partner * 16 + i4 * 4];
        ov[i4*4+0]=t1.x; ov[i4*4+1]=t1.y; ov[i4*4+2]=t1.z; ov[i4*4+3]=t1.w;
      }

      // ---- rotation angle (both pair members compute bit-identical c,s) ----
      float c, s;
      if (fabsf(apq) < 1e-30f) { c = 1.f; s = 0.f; }
      else {
        float theta = (aqq - app) / (2.f * apq);
        float t = 1.f / (fabsf(theta) + sqrtf(fmaf(theta, theta, 1.f)));
        t = (theta < 0.f) ? -t : t;
        c = rsqrtf(fmaf(t, t, 1.f));
        s = t * c;
      }

      // ---- publish (c,s) for the row-update of every column ----
      int kidx;
      if (sub == 15) kidx = 0;
      else { int d = sub - r; if (d < 0) d += 15; kidx = (d == 0) ? 0 : ((d <= 7) ? d : 15 - d); }
      cs[kidx] = make_float2(c, s);
      __syncthreads();

      // ---- column mix: col_p' = c*col_p - s*col_q ; col_q' = s*col_p + c*col_q ----
      const float sgn = amP ? -s : s;
#pragma unroll
      for (int i = 0; i < 16; ++i) {
        a[i] = fmaf(sgn, oa[i], c * a[i]);
        v[i] = fmaf(sgn, ov[i], c * v[i]);
      }

      // ---- row mix for all 8 pairs (pk,qk compile-time via unroll) ----
#pragma unroll
      for (int k = 0; k < 8; ++k) {
        int pk, qk;
        if (k == 0) { pk = r; qk = 15; }
        else {
          int u = r + k;      if (u >= 15) u -= 15;
          int w = r + 15 - k; if (w >= 15) w -= 15;
          pk = u < w ? u : w; qk = u < w ? w : u;
        }
        float2 ck = cs[k];
        float tp = a[pk], tq = a[qk];
        a[pk] = fmaf(-ck.y, tq, ck.x * tp);
        a[qk] = fmaf( ck.y, tp, ck.x * tq);
      }

      // ---- write back own columns ----
#pragma unroll
      for (int i4 = 0; i4 < 4; ++i4) {
        *(float4*)&Acol[sub * 16 + i4 * 4] = make_float4(a[i4*4], a[i4*4+1], a[i4*4+2], a[i4*4+3]);
        *(float4*)&Vcol[sub * 16 + i4 * 4] = make_float4(v[i4*4], v[i4*4+1], v[i4*4+2], v[i4*4+3]);
      }
      __syncthreads();
    }
  }
}

// ---------------------------------------------------------------------------
// K1: log_eig(S) -> tril vector [NMAT,136]
// ---------------------------------------------------------------------------
__global__ __launch_bounds__(256) void k1_logvec(const float* __restrict__ S, float* __restrict__ vec) {
  __shared__ float Ald[16 * MAT_STRIDE];
  __shared__ float Vld[16 * MAT_STRIDE];
  __shared__ float2 csld[16 * 8];
  __shared__ float lwld[16 * 16];
  const int tid = threadIdx.x;
  const int mloc = tid >> 4;
  const int sub = tid & 15;
  const int mat = blockIdx.x * 16 + mloc;
  float* Acol = &Ald[mloc * MAT_STRIDE];
  float* Vcol = &Vld[mloc * MAT_STRIDE];
  float2* cs = &csld[mloc * 8];
  float a[16], v[16];
  const float* Sp = S + (size_t)mat * 256;
#pragma unroll
  for (int i = 0; i < 16; ++i) { a[i] = Sp[i * 16 + sub]; v[i] = (i == sub) ? 1.f : 0.f; }
#pragma unroll
  for (int i4 = 0; i4 < 4; ++i4) {
    *(float4*)&Acol[sub * 16 + i4*4] = make_float4(a[i4*4],a[i4*4+1],a[i4*4+2],a[i4*4+3]);
    *(float4*)&Vcol[sub * 16 + i4*4] = make_float4(v[i4*4],v[i4*4+1],v[i4*4+2],v[i4*4+3]);
  }
  jacobi16(Acol, Vcol, cs, a, v, sub);
  const float lam = Acol[sub * 16 + sub];
  lwld[mloc * 16 + sub] = logf(fmaxf(lam, 1e-8f));
  __syncthreads();
  // logS_{r,c} = sum_j lw_j * V_{r,j} * V_{c,j}; V stored column-major: V_{i,j}=Vcol[j*16+i]
  for (int idx = sub; idx < DIMV; idx += 16) {
    int rr = (int)((sqrtf(8.f * (float)idx + 1.f) - 1.f) * 0.5f);
    while ((rr + 1) * (rr + 2) / 2 <= idx) ++rr;
    while (rr * (rr + 1) / 2 > idx) --rr;
    int ccol = idx - rr * (rr + 1) / 2;
    float acc = 0.f;
#pragma unroll
    for (int j = 0; j < 16; ++j)
      acc += lwld[mloc * 16 + j] * Vcol[j * 16 + rr] * Vcol[j * 16 + ccol];
    vec[(size_t)mat * DIMV + idx] = acc;
  }
}

// ---------------------------------------------------------------------------
// K2: QKV projection  Y[16384,408] = X[16384,136] @ W^T + b
// thread = (row, group of 8 output cols); 51 groups cover 408.
// ---------------------------------------------------------------------------
__global__ __launch_bounds__(256) void k2_qkv(const float* __restrict__ X, const float* __restrict__ W,
                                              const float* __restrict__ bias, float* __restrict__ Y) {
  const int gid = blockIdx.x * 256 + threadIdx.x;
  const int row = gid / 51;
  const int g = gid - row * 51;
  const int n0 = g * 8;
  const float4* x4 = (const float4*)(X + (size_t)row * DIMV);
  float acc[8];
#pragma unroll
  for (int j = 0; j < 8; ++j) acc[j] = bias[n0 + j];
#pragma unroll 2
  for (int k4 = 0; k4 < 34; ++k4) {
    float4 xv = x4[k4];
#pragma unroll
    for (int j = 0; j < 8; ++j) {
      float4 wv = *(const float4*)(W + (size_t)(n0 + j) * DIMV + k4 * 4);
      acc[j] = fmaf(xv.x, wv.x, acc[j]);
      acc[j] = fmaf(xv.y, wv.y, acc[j]);
      acc[j] = fmaf(xv.z, wv.z, acc[j]);
      acc[j] = fmaf(xv.w, wv.w, acc[j]);
    }
  }
  float* yp = Y + (size_t)row * QKVD + n0;
  *(float4*)(yp)     = make_float4(acc[0], acc[1], acc[2], acc[3]);
  *(float4*)(yp + 4) = make_float4(acc[4], acc[5], acc[6], acc[7]);
}

// ---------------------------------------------------------------------------
// K3: full attention, one thread per (b,h,q-row), online softmax over 32-key
// tiles staged in LDS (rows padded 34->36 floats for aligned float4 reads).
// ---------------------------------------------------------------------------
__global__ __launch_bounds__(256, 1) void k3_attn(const float* __restrict__ QKV, float* __restrict__ O) {
  __shared__ float Kt[32 * 36];
  __shared__ float Vt[32 * 36];
  const int b = blockIdx.x >> 2;
  const int h = blockIdx.x & 3;
  const int qrow = blockIdx.y * 256 + threadIdx.x;
  const float scale = 0.1714985851425088f;  // 1/sqrt(34)
  float q[36], o[36];
  const float* qp = QKV + ((size_t)(b * L_SZ + qrow)) * QKVD + h * HD;
#pragma unroll
  for (int d = 0; d < HD; ++d) q[d] = qp[d] * scale;
  q[34] = 0.f; q[35] = 0.f;
#pragma unroll
  for (int d = 0; d < 36; ++d) o[d] = 0.f;
  float m = -1e30f, l = 0.f;

  for (int t = 0; t < 32; ++t) {
    __syncthreads();
    const size_t kbase = ((size_t)(b * L_SZ + t * 32)) * QKVD;
    for (int e = threadIdx.x; e < 32 * HD; e += 256) {
      int kk = e / HD, d = e - kk * HD;
      Kt[kk * 36 + d] = QKV[kbase + (size_t)kk * QKVD + DIMV + h * HD + d];
      Vt[kk * 36 + d] = QKV[kbase + (size_t)kk * QKVD + 2 * DIMV + h * HD + d];
    }
    for (int e = threadIdx.x; e < 64; e += 256) {
      int kk = e >> 1, d = 34 + (e & 1);
      Kt[kk * 36 + d] = 0.f; Vt[kk * 36 + d] = 0.f;
    }
    __syncthreads();

    float s[32];
#pragma unroll
    for (int kk = 0; kk < 32; ++kk) {
      const float4* kr = (const float4*)&Kt[kk * 36];
      float acc = 0.f;
#pragma unroll
      for (int d4 = 0; d4 < 9; ++d4) {
        float4 kv = kr[d4];
        acc = fmaf(q[d4*4+0], kv.x, acc);
        acc = fmaf(q[d4*4+1], kv.y, acc);
        acc = fmaf(q[d4*4+2], kv.z, acc);
        acc = fmaf(q[d4*4+3], kv.w, acc);
      }
      s[kk] = acc;
    }
    float tmax = s[0];
#pragma unroll
    for (int kk = 1; kk < 32; ++kk) tmax = fmaxf(tmax, s[kk]);
    const float mn = fmaxf(m, tmax);
    const float corr = __expf(m - mn);   // first tile: exp(-1e30-mn) -> 0, no NaN
    l *= corr;
#pragma unroll
    for (int d = 0; d < 36; ++d) o[d] *= corr;
#pragma unroll
    for (int kk = 0; kk < 32; ++kk) {
      float p = __expf(s[kk] - mn);
      l += p;
      const float4* vr = (const float4*)&Vt[kk * 36];
#pragma unroll
      for (int d4 = 0; d4 < 9; ++d4) {
        float4 vv = vr[d4];
        o[d4*4+0] = fmaf(p, vv.x, o[d4*4+0]);
        o[d4*4+1] = fmaf(p, vv.y, o[d4*4+1]);
        o[d4*4+2] = fmaf(p, vv.z, o[d4*4+2]);
        o[d4*4+3] = fmaf(p, vv.w, o[d4*4+3]);
      }
    }
    m = mn;
  }
  const float inv = 1.f / l;
  float* op = O + ((size_t)(b * L_SZ + qrow)) * DIMV + h * HD;
#pragma unroll
  for (int d = 0; d < HD; ++d) op[d] = o[d] * inv;
}

// ---------------------------------------------------------------------------
// K4: out-projection + residual: vec_out = attn @ out_w^T + out_b + vec_in
// ---------------------------------------------------------------------------
__global__ __launch_bounds__(256) void k4_outproj(const float* __restrict__ X, const float* __restrict__ W,
                                                  const float* __restrict__ bias, const float* __restrict__ resid,
                                                  float* __restrict__ Y) {
  const int gid = blockIdx.x * 256 + threadIdx.x;
  const int row = gid / 17;
  const int g = gid - row * 17;
  const int n0 = g * 8;
  const float4* x4 = (const float4*)(X + (size_t)row * DIMV);
  float acc[8];
#pragma unroll
  for (int j = 0; j < 8; ++j) acc[j] = bias[n0 + j];
#pragma unroll 2
  for (int k4 = 0; k4 < 34; ++k4) {
    float4 xv = x4[k4];
#pragma unroll
    for (int j = 0; j < 8; ++j) {
      float4 wv = *(const float4*)(W + (size_t)(n0 + j) * DIMV + k4 * 4);
      acc[j] = fmaf(xv.x, wv.x, acc[j]);
      acc[j] = fmaf(xv.y, wv.y, acc[j]);
      acc[j] = fmaf(xv.z, wv.z, acc[j]);
      acc[j] = fmaf(xv.w, wv.w, acc[j]);
    }
  }
  const float4* r4 = (const float4*)(resid + (size_t)row * DIMV + n0);
  float4 r0 = r4[0], r1 = r4[1];
  float* yp = Y + (size_t)row * DIMV + n0;
  *(float4*)(yp)     = make_float4(acc[0]+r0.x, acc[1]+r0.y, acc[2]+r0.z, acc[3]+r0.w);
  *(float4*)(yp + 4) = make_float4(acc[4]+r1.x, acc[5]+r1.y, acc[6]+r1.z, acc[7]+r1.w);
}

// ---------------------------------------------------------------------------
// K5: rebuild symmetric matrix from vec_out, exp_eig, write full 16x16 output
// ---------------------------------------------------------------------------
__global__ __launch_bounds__(256) void k5_expm(const float* __restrict__ vecOut, float* __restrict__ out) {
  __shared__ float Ald[16 * MAT_STRIDE];
  __shared__ float Vld[16 * MAT_STRIDE];
  __shared__ float2 csld[16 * 8];
  __shared__ float eld[16 * 16];
  const int tid = threadIdx.x;
  const int mloc = tid >> 4;
  const int sub = tid & 15;
  const int mat = blockIdx.x * 16 + mloc;
  float* Acol = &Ald[mloc * MAT_STRIDE];
  float* Vcol = &Vld[mloc * MAT_STRIDE];
  float2* cs = &csld[mloc * 8];
  float a[16], v[16];
  const float* vp = vecOut + (size_t)mat * DIMV;
#pragma unroll
  for (int i = 0; i < 16; ++i) {
    int rr = i > sub ? i : sub;
    int cc = i > sub ? sub : i;
    a[i] = vp[rr * (rr + 1) / 2 + cc];
    v[i] = (i == sub) ? 1.f : 0.f;
  }
#pragma unroll
  for (int i4 = 0; i4 < 4; ++i4) {
    *(float4*)&Acol[sub * 16 + i4*4] = make_float4(a[i4*4],a[i4*4+1],a[i4*4+2],a[i4*4+3]);
    *(float4*)&Vcol[sub * 16 + i4*4] = make_float4(v[i4*4],v[i4*4+1],v[i4*4+2],v[i4*4+3]);
  }
  jacobi16(Acol, Vcol, cs, a, v, sub);
  eld[mloc * 16 + sub] = expf(Acol[sub * 16 + sub]);
  __syncthreads();
  // O_{i,j} = sum_m e_m V_{i,m} V_{j,m}; this thread computes column j=sub
  float u[16];
#pragma unroll
  for (int j = 0; j < 16; ++j) u[j] = eld[mloc * 16 + j] * Vcol[j * 16 + sub];
#pragma unroll
  for (int i = 0; i < 16; ++i) {
    float acc = 0.f;
#pragma unroll
    for (int j = 0; j < 16; ++j) acc = fmaf(u[j], Vcol[j * 16 + i], acc);
    out[(size_t)mat * 256 + i * 16 + sub] = acc;
  }
}

// ---------------------------------------------------------------------------
extern "C" void kernel_launch(void* const* d_in, const int* in_sizes, int n_in,
                              void* d_out, int out_size, void* d_ws, size_t ws_size,
                              hipStream_t stream) {
  const float* S     = (const float*)d_in[0];
  const float* in_w  = (const float*)d_in[1];
  const float* in_b  = (const float*)d_in[2];
  const float* out_w = (const float*)d_in[3];
  const float* out_b = (const float*)d_in[4];
  float* out = (float*)d_out;
  float* ws = (float*)d_ws;
  // workspace layout (f32): vec_in[16384*136] | qkv[16384*408] | attn[16384*136] | vec_out[16384*136]
  float* vec_in  = ws;
  float* qkv     = vec_in + (size_t)NMAT * DIMV;
  float* attn    = qkv    + (size_t)NMAT * QKVD;
  float* vec_out = attn   + (size_t)NMAT * DIMV;

  k1_logvec <<<dim3(NMAT / 16),        dim3(256), 0, stream>>>(S, vec_in);
  k2_qkv    <<<dim3((NMAT * 51) / 256), dim3(256), 0, stream>>>(vec_in, in_w, in_b, qkv);
  k3_attn   <<<dim3(64, 4),            dim3(256), 0, stream>>>(qkv, attn);
  k4_outproj<<<dim3((NMAT * 17) / 256), dim3(256), 0, stream>>>(attn, out_w, out_b, vec_in, vec_out);
  k5_expm   <<<dim3(NMAT / 16),        dim3(256), 0, stream>>>(vec_out, out);
}

// Round 2
// 1714.977 us; speedup vs baseline: 1.3744x; 1.3744x over previous
//
#include <hip/hip_runtime.h>
#include <math.h>

#define B_SZ 16
#define L_SZ 1024
#define NMAT (B_SZ * L_SZ)   // 16384
#define DIMV 136
#define QKVD 408
#define HD 34
#define NH 4
#define NSWEEP 8
#define MAT_STRIDE 260       // per-matrix LDS stride (256 + 4 pad to spread banks)

// ---------------------------------------------------------------------------
// Parallel cyclic Jacobi eigensolver for one 16x16 symmetric matrix per
// 16-lane group. Own column lives in registers (a[16]); LDS mirror (Acol)
// provides partner-column access and scalar picks (runtime indices OK in
// LDS). V accumulated identically (column-mix only). Round-robin pairing:
// round r pairs (r,15) and ((r+k)%15,(r-k)%15) k=1..7 -- all disjoint.
// Loops over r and k are fully unrolled so register indices are static.
// ---------------------------------------------------------------------------
__device__ __forceinline__ void jacobi16(float* __restrict__ Acol, float* __restrict__ Vcol,
                                         float2* __restrict__ cs, float a[16], float v[16],
                                         const int sub) {
  __syncthreads();  // LDS init visible
  for (int sweep = 0; sweep < NSWEEP; ++sweep) {
#pragma unroll
    for (int r = 0; r < 15; ++r) {
      // ---- pairing (r is compile-time; sub is a runtime value, not an index) ----
      int partner;
      if (sub == 15) partner = r;
      else {
        int d = sub - r; if (d < 0) d += 15;
        if (d == 0) partner = 15;
        else if (d <= 7) { partner = r - d; if (partner < 0) partner += 15; }
        else { partner = r + 15 - d; if (partner >= 15) partner -= 15; }
      }
      const bool amP = (sub < partner);
      const int p_ = amP ? sub : partner;
      const int q_ = amP ? partner : sub;

      // ---- read pivot scalars + partner columns from LDS (current state) ----
      const float app = Acol[p_ * 16 + p_];
      const float aqq = Acol[q_ * 16 + q_];
      const float apq = Acol[p_ * 16 + q_];
      float oa[16], ov[16];
#pragma unroll
      for (int i4 = 0; i4 < 4; ++i4) {
        float4 t0 = *(const float4*)&Acol[partner * 16 + i4 * 4];
        oa[i4*4+0]=t0.x; oa[i4*4+1]=t0.y; oa[i4*4+2]=t0.z; oa[i4*4+3]=t0.w;
        float4 t1 = *(const float4*)&Vcol[partner * 16 + i4 * 4];
        ov[i4*4+0]=t1.x; ov[i4*4+1]=t1.y; ov[i4*4+2]=t1.z; ov[i4*4+3]=t1.w;
      }

      // ---- rotation angle (both pair members compute bit-identical c,s) ----
      float c, s;
      if (fabsf(apq) < 1e-30f) { c = 1.f; s = 0.f; }
      else {
        float theta = (aqq - app) / (2.f * apq);
        float t = 1.f / (fabsf(theta) + sqrtf(fmaf(theta, theta, 1.f)));
        t = (theta < 0.f) ? -t : t;
        c = rsqrtf(fmaf(t, t, 1.f));
        s = t * c;
      }

      // ---- publish (c,s) for the row-update of every column ----
      int kidx;
      if (sub == 15) kidx = 0;
      else { int d = sub - r; if (d < 0) d += 15; kidx = (d == 0) ? 0 : ((d <= 7) ? d : 15 - d); }
      cs[kidx] = make_float2(c, s);
      __syncthreads();

      // ---- column mix: col_p' = c*col_p - s*col_q ; col_q' = s*col_p + c*col_q ----
      const float sgn = amP ? -s : s;
#pragma unroll
      for (int i = 0; i < 16; ++i) {
        a[i] = fmaf(sgn, oa[i], c * a[i]);
        v[i] = fmaf(sgn, ov[i], c * v[i]);
      }

      // ---- row mix for all 8 pairs (pk,qk compile-time via unroll) ----
#pragma unroll
      for (int k = 0; k < 8; ++k) {
        int pk, qk;
        if (k == 0) { pk = r; qk = 15; }
        else {
          int u = r + k;      if (u >= 15) u -= 15;
          int w = r + 15 - k; if (w >= 15) w -= 15;
          pk = u < w ? u : w; qk = u < w ? w : u;
        }
        float2 ck = cs[k];
        float tp = a[pk], tq = a[qk];
        a[pk] = fmaf(-ck.y, tq, ck.x * tp);
        a[qk] = fmaf( ck.y, tp, ck.x * tq);
      }

      // ---- write back own columns ----
#pragma unroll
      for (int i4 = 0; i4 < 4; ++i4) {
        *(float4*)&Acol[sub * 16 + i4 * 4] = make_float4(a[i4*4], a[i4*4+1], a[i4*4+2], a[i4*4+3]);
        *(float4*)&Vcol[sub * 16 + i4 * 4] = make_float4(v[i4*4], v[i4*4+1], v[i4*4+2], v[i4*4+3]);
      }
      __syncthreads();
    }
  }
}

// ---------------------------------------------------------------------------
// K1: log_eig(S) -> tril vector [NMAT,136]
// ---------------------------------------------------------------------------
__global__ __launch_bounds__(256) void k1_logvec(const float* __restrict__ S, float* __restrict__ vec) {
  __shared__ float Ald[16 * MAT_STRIDE];
  __shared__ float Vld[16 * MAT_STRIDE];
  __shared__ float2 csld[16 * 8];
  __shared__ float lwld[16 * 16];
  const int tid = threadIdx.x;
  const int mloc = tid >> 4;
  const int sub = tid & 15;
  const int mat = blockIdx.x * 16 + mloc;
  float* Acol = &Ald[mloc * MAT_STRIDE];
  float* Vcol = &Vld[mloc * MAT_STRIDE];
  float2* cs = &csld[mloc * 8];
  float a[16], v[16];
  const float* Sp = S + (size_t)mat * 256;
#pragma unroll
  for (int i = 0; i < 16; ++i) { a[i] = Sp[i * 16 + sub]; v[i] = (i == sub) ? 1.f : 0.f; }
#pragma unroll
  for (int i4 = 0; i4 < 4; ++i4) {
    *(float4*)&Acol[sub * 16 + i4*4] = make_float4(a[i4*4],a[i4*4+1],a[i4*4+2],a[i4*4+3]);
    *(float4*)&Vcol[sub * 16 + i4*4] = make_float4(v[i4*4],v[i4*4+1],v[i4*4+2],v[i4*4+3]);
  }
  jacobi16(Acol, Vcol, cs, a, v, sub);
  const float lam = Acol[sub * 16 + sub];
  lwld[mloc * 16 + sub] = logf(fmaxf(lam, 1e-8f));
  __syncthreads();
  // logS_{r,c} = sum_j lw_j * V_{r,j} * V_{c,j}; V stored column-major: V_{i,j}=Vcol[j*16+i]
  for (int idx = sub; idx < DIMV; idx += 16) {
    int rr = (int)((sqrtf(8.f * (float)idx + 1.f) - 1.f) * 0.5f);
    while ((rr + 1) * (rr + 2) / 2 <= idx) ++rr;
    while (rr * (rr + 1) / 2 > idx) --rr;
    int ccol = idx - rr * (rr + 1) / 2;
    float acc = 0.f;
#pragma unroll
    for (int j = 0; j < 16; ++j)
      acc += lwld[mloc * 16 + j] * Vcol[j * 16 + rr] * Vcol[j * 16 + ccol];
    vec[(size_t)mat * DIMV + idx] = acc;
  }
}

// ---------------------------------------------------------------------------
// K2: QKV projection  Y[16384,408] = X[16384,136] @ W^T + b
// One thread per row; 24 col-groups of 17 cols (blockIdx.y). W/bias indices
// are wave-uniform (blockIdx + unrolled loop vars only) -> scalar loads,
// L1-resident chunk (9.2 KB). X row streams one float4 at a time.
// ---------------------------------------------------------------------------
__global__ __launch_bounds__(256) void k2_qkv(const float* __restrict__ X, const float* __restrict__ W,
                                              const float* __restrict__ bias, float* __restrict__ Y) {
  const int row = blockIdx.x * 256 + threadIdx.x;
  const int n0 = blockIdx.y * 17;
  const float4* __restrict__ x4 = (const float4*)(X + (size_t)row * DIMV);
  const float4* __restrict__ w4 = (const float4*)W;
  float acc[17];
#pragma unroll
  for (int c = 0; c < 17; ++c) acc[c] = bias[n0 + c];
#pragma unroll 2
  for (int k4 = 0; k4 < 34; ++k4) {
    const float4 xv = x4[k4];
#pragma unroll
    for (int c = 0; c < 17; ++c) {
      const float4 wv = w4[(size_t)(n0 + c) * 34 + k4];
      acc[c] = fmaf(xv.x, wv.x, acc[c]);
      acc[c] = fmaf(xv.y, wv.y, acc[c]);
      acc[c] = fmaf(xv.z, wv.z, acc[c]);
      acc[c] = fmaf(xv.w, wv.w, acc[c]);
    }
  }
  float* yp = Y + (size_t)row * QKVD + n0;
#pragma unroll
  for (int c = 0; c < 17; ++c) yp[c] = acc[c];
}

// ---------------------------------------------------------------------------
// K3: full attention, one thread per (b,h,q-row), online softmax over 32-key
// tiles staged in LDS (rows padded 34->36 floats for aligned float4 reads).
// ---------------------------------------------------------------------------
__global__ __launch_bounds__(256, 1) void k3_attn(const float* __restrict__ QKV, float* __restrict__ O) {
  __shared__ float Kt[32 * 36];
  __shared__ float Vt[32 * 36];
  const int b = blockIdx.x >> 2;
  const int h = blockIdx.x & 3;
  const int qrow = blockIdx.y * 256 + threadIdx.x;
  const float scale = 0.1714985851425088f;  // 1/sqrt(34)
  float q[36], o[36];
  const float* qp = QKV + ((size_t)(b * L_SZ + qrow)) * QKVD + h * HD;
#pragma unroll
  for (int d = 0; d < HD; ++d) q[d] = qp[d] * scale;
  q[34] = 0.f; q[35] = 0.f;
#pragma unroll
  for (int d = 0; d < 36; ++d) o[d] = 0.f;
  float m = -1e30f, l = 0.f;

  for (int t = 0; t < 32; ++t) {
    __syncthreads();
    const size_t kbase = ((size_t)(b * L_SZ + t * 32)) * QKVD;
    for (int e = threadIdx.x; e < 32 * HD; e += 256) {
      int kk = e / HD, d = e - kk * HD;
      Kt[kk * 36 + d] = QKV[kbase + (size_t)kk * QKVD + DIMV + h * HD + d];
      Vt[kk * 36 + d] = QKV[kbase + (size_t)kk * QKVD + 2 * DIMV + h * HD + d];
    }
    for (int e = threadIdx.x; e < 64; e += 256) {
      int kk = e >> 1, d = 34 + (e & 1);
      Kt[kk * 36 + d] = 0.f; Vt[kk * 36 + d] = 0.f;
    }
    __syncthreads();

    float s[32];
#pragma unroll
    for (int kk = 0; kk < 32; ++kk) {
      const float4* kr = (const float4*)&Kt[kk * 36];
      float acc = 0.f;
#pragma unroll
      for (int d4 = 0; d4 < 9; ++d4) {
        float4 kv = kr[d4];
        acc = fmaf(q[d4*4+0], kv.x, acc);
        acc = fmaf(q[d4*4+1], kv.y, acc);
        acc = fmaf(q[d4*4+2], kv.z, acc);
        acc = fmaf(q[d4*4+3], kv.w, acc);
      }
      s[kk] = acc;
    }
    float tmax = s[0];
#pragma unroll
    for (int kk = 1; kk < 32; ++kk) tmax = fmaxf(tmax, s[kk]);
    const float mn = fmaxf(m, tmax);
    const float corr = __expf(m - mn);   // first tile: exp(-1e30-mn) -> 0, no NaN
    l *= corr;
#pragma unroll
    for (int d = 0; d < 36; ++d) o[d] *= corr;
#pragma unroll
    for (int kk = 0; kk < 32; ++kk) {
      float p = __expf(s[kk] - mn);
      l += p;
      const float4* vr = (const float4*)&Vt[kk * 36];
#pragma unroll
      for (int d4 = 0; d4 < 9; ++d4) {
        float4 vv = vr[d4];
        o[d4*4+0] = fmaf(p, vv.x, o[d4*4+0]);
        o[d4*4+1] = fmaf(p, vv.y, o[d4*4+1]);
        o[d4*4+2] = fmaf(p, vv.z, o[d4*4+2]);
        o[d4*4+3] = fmaf(p, vv.w, o[d4*4+3]);
      }
    }
    m = mn;
  }
  const float inv = 1.f / l;
  float* op = O + ((size_t)(b * L_SZ + qrow)) * DIMV + h * HD;
#pragma unroll
  for (int d = 0; d < HD; ++d) op[d] = o[d] * inv;
}

// ---------------------------------------------------------------------------
// K4: out-projection + residual, same wave-uniform-W structure as K2.
// N=136 = 8 col-groups of 17.
// ---------------------------------------------------------------------------
__global__ __launch_bounds__(256) void k4_outproj(const float* __restrict__ X, const float* __restrict__ W,
                                                  const float* __restrict__ bias, const float* __restrict__ resid,
                                                  float* __restrict__ Y) {
  const int row = blockIdx.x * 256 + threadIdx.x;
  const int n0 = blockIdx.y * 17;
  const float4* __restrict__ x4 = (const float4*)(X + (size_t)row * DIMV);
  const float4* __restrict__ w4 = (const float4*)W;
  float acc[17];
#pragma unroll
  for (int c = 0; c < 17; ++c) acc[c] = bias[n0 + c];
#pragma unroll 2
  for (int k4 = 0; k4 < 34; ++k4) {
    const float4 xv = x4[k4];
#pragma unroll
    for (int c = 0; c < 17; ++c) {
      const float4 wv = w4[(size_t)(n0 + c) * 34 + k4];
      acc[c] = fmaf(xv.x, wv.x, acc[c]);
      acc[c] = fmaf(xv.y, wv.y, acc[c]);
      acc[c] = fmaf(xv.z, wv.z, acc[c]);
      acc[c] = fmaf(xv.w, wv.w, acc[c]);
    }
  }
  const float* rp = resid + (size_t)row * DIMV + n0;
  float* yp = Y + (size_t)row * DIMV + n0;
#pragma unroll
  for (int c = 0; c < 17; ++c) yp[c] = acc[c] + rp[c];
}

// ---------------------------------------------------------------------------
// K5: rebuild symmetric matrix from vec_out, exp_eig, write full 16x16 output
// ---------------------------------------------------------------------------
__global__ __launch_bounds__(256) void k5_expm(const float* __restrict__ vecOut, float* __restrict__ out) {
  __shared__ float Ald[16 * MAT_STRIDE];
  __shared__ float Vld[16 * MAT_STRIDE];
  __shared__ float2 csld[16 * 8];
  __shared__ float eld[16 * 16];
  const int tid = threadIdx.x;
  const int mloc = tid >> 4;
  const int sub = tid & 15;
  const int mat = blockIdx.x * 16 + mloc;
  float* Acol = &Ald[mloc * MAT_STRIDE];
  float* Vcol = &Vld[mloc * MAT_STRIDE];
  float2* cs = &csld[mloc * 8];
  float a[16], v[16];
  const float* vp = vecOut + (size_t)mat * DIMV;
#pragma unroll
  for (int i = 0; i < 16; ++i) {
    int rr = i > sub ? i : sub;
    int cc = i > sub ? sub : i;
    a[i] = vp[rr * (rr + 1) / 2 + cc];
    v[i] = (i == sub) ? 1.f : 0.f;
  }
#pragma unroll
  for (int i4 = 0; i4 < 4; ++i4) {
    *(float4*)&Acol[sub * 16 + i4*4] = make_float4(a[i4*4],a[i4*4+1],a[i4*4+2],a[i4*4+3]);
    *(float4*)&Vcol[sub * 16 + i4*4] = make_float4(v[i4*4],v[i4*4+1],v[i4*4+2],v[i4*4+3]);
  }
  jacobi16(Acol, Vcol, cs, a, v, sub);
  eld[mloc * 16 + sub] = expf(Acol[sub * 16 + sub]);
  __syncthreads();
  // O_{i,j} = sum_m e_m V_{i,m} V_{j,m}; this thread computes column j=sub
  float u[16];
#pragma unroll
  for (int j = 0; j < 16; ++j) u[j] = eld[mloc * 16 + j] * Vcol[j * 16 + sub];
#pragma unroll
  for (int i = 0; i < 16; ++i) {
    float acc = 0.f;
#pragma unroll
    for (int j = 0; j < 16; ++j) acc = fmaf(u[j], Vcol[j * 16 + i], acc);
    out[(size_t)mat * 256 + i * 16 + sub] = acc;
  }
}

// ---------------------------------------------------------------------------
extern "C" void kernel_launch(void* const* d_in, const int* in_sizes, int n_in,
                              void* d_out, int out_size, void* d_ws, size_t ws_size,
                              hipStream_t stream) {
  const float* S     = (const float*)d_in[0];
  const float* in_w  = (const float*)d_in[1];
  const float* in_b  = (const float*)d_in[2];
  const float* out_w = (const float*)d_in[3];
  const float* out_b = (const float*)d_in[4];
  float* out = (float*)d_out;
  float* ws = (float*)d_ws;
  // workspace layout (f32): vec_in[16384*136] | qkv[16384*408] | attn[16384*136] | vec_out[16384*136]
  float* vec_in  = ws;
  float* qkv     = vec_in + (size_t)NMAT * DIMV;
  float* attn    = qkv    + (size_t)NMAT * QKVD;
  float* vec_out = attn   + (size_t)NMAT * DIMV;

  k1_logvec <<<dim3(NMAT / 16),     dim3(256), 0, stream>>>(S, vec_in);
  k2_qkv    <<<dim3(NMAT / 256, 24), dim3(256), 0, stream>>>(vec_in, in_w, in_b, qkv);
  k3_attn   <<<dim3(64, 4),          dim3(256), 0, stream>>>(qkv, attn);
  k4_outproj<<<dim3(NMAT / 256, 8),  dim3(256), 0, stream>>>(attn, out_w, out_b, vec_in, vec_out);
  k5_expm   <<<dim3(NMAT / 16),      dim3(256), 0, stream>>>(vec_out, out);
}

// Round 3
// 1057.624 us; speedup vs baseline: 2.2286x; 1.6215x over previous
//
#include <hip/hip_runtime.h>
#include <math.h>

#define B_SZ 16
#define L_SZ 1024
#define NMAT (B_SZ * L_SZ)   // 16384
#define DIMV 136
#define QKVD 408
#define HD 34
#define NH 4
#define NSWEEP 8

// ---------------------------------------------------------------------------
// Extract a[j] for runtime j from a statically-indexed register array via a
// 15-cndmask binary select tree (no scratch spill).
// ---------------------------------------------------------------------------
__device__ __forceinline__ float sel16(const float a[16], int j) {
  float p0 = (j & 1) ? a[1] : a[0];
  float p1 = (j & 1) ? a[3] : a[2];
  float p2 = (j & 1) ? a[5] : a[4];
  float p3 = (j & 1) ? a[7] : a[6];
  float p4 = (j & 1) ? a[9] : a[8];
  float p5 = (j & 1) ? a[11] : a[10];
  float p6 = (j & 1) ? a[13] : a[12];
  float p7 = (j & 1) ? a[15] : a[14];
  float q0 = (j & 2) ? p1 : p0;
  float q1 = (j & 2) ? p3 : p2;
  float q2 = (j & 2) ? p5 : p4;
  float q3 = (j & 2) ? p7 : p6;
  float r0 = (j & 4) ? q1 : q0;
  float r1 = (j & 4) ? q3 : q2;
  return (j & 8) ? r1 : r0;
}

// ---------------------------------------------------------------------------
// Parallel cyclic Jacobi, one 16x16 symmetric matrix per 16-lane group,
// entirely in registers + wave shuffles (ds_bpermute): no LDS, no barriers,
// no bank conflicts. Lane sub owns column sub of A and V plus its diagonal
// entry. Chess-tournament pairing: round r pairs (r,15) and
// ((r+k)%15,(r-k)%15) k=1..7 (disjoint). Pivot apq is single-sourced from
// the p-member so both pair members compute bit-identical (c,s).
// ---------------------------------------------------------------------------
__device__ __forceinline__ void jacobi16_reg(float a[16], float v[16], float& diag,
                                             const int lane) {
  const int sub = lane & 15;
  const int gbase = lane & 48;
  for (int sweep = 0; sweep < NSWEEP; ++sweep) {
#pragma unroll
    for (int r = 0; r < 15; ++r) {
      // ---- my partner this round ----
      int partner;
      if (sub == 15) partner = r;
      else {
        int d = sub - r; if (d < 0) d += 15;
        if (d == 0) partner = 15;
        else if (d <= 7) { partner = r - d; if (partner < 0) partner += 15; }
        else { partner = r + 15 - d; if (partner >= 15) partner -= 15; }
      }
      const int plane = gbase | partner;

      // ---- exchange columns + diagonal via shuffles ----
      float oa[16], ov[16];
#pragma unroll
      for (int i = 0; i < 16; ++i) oa[i] = __shfl(a[i], plane);
#pragma unroll
      for (int i = 0; i < 16; ++i) ov[i] = __shfl(v[i], plane);
      const float diag_o = __shfl(diag, plane);
      const bool amP = sub < partner;
      const float app = amP ? diag : diag_o;
      const float aqq = amP ? diag_o : diag;
      // apq = A[q][p]: p-member extracts its column entry at row q; broadcast
      // from the p-member so both members use the identical value.
      const float apq_loc = sel16(a, partner);
      const int pl = gbase | (amP ? sub : partner);
      const float apq = __shfl(apq_loc, pl);

      // ---- rotation angle (identical on both members) ----
      float c, s;
      {
        float theta = (aqq - app) / (2.f * apq);
        float t = 1.f / (fabsf(theta) + sqrtf(fmaf(theta, theta, 1.f)));
        t = (theta < 0.f) ? -t : t;
        t = (fabsf(apq) < 1e-30f) ? 0.f : t;   // also kills theta=NaN case
        c = rsqrtf(fmaf(t, t, 1.f));
        s = t * c;
      }

      // ---- column mix: col_p' = c p - s q ; col_q' = s p + c q ----
      const float sgn = amP ? -s : s;
#pragma unroll
      for (int i = 0; i < 16; ++i) {
        a[i] = fmaf(sgn, oa[i], c * a[i]);
        v[i] = fmaf(sgn, ov[i], c * v[i]);
      }

      // ---- diagonal via closed-form 2-sided rotation ----
      const float cc = c * c, ss2 = s * s, cs2 = 2.f * c * s;
      const float dp = fmaf(cc, app, fmaf(ss2, aqq, -cs2 * apq));
      const float dq = fmaf(ss2, app, fmaf(cc, aqq, cs2 * apq));
      diag = amP ? dp : dq;

      // ---- row mix for all 8 pairs; (c,s) broadcast from compile-time owner ----
#pragma unroll
      for (int k = 0; k < 8; ++k) {
        const int owner = (k == 0) ? r : (r + k) % 15;    // compile-time
        float ck = __shfl(c, gbase | owner);
        float sk = __shfl(s, gbase | owner);
        int pk, qk;
        if (k == 0) { pk = r; qk = 15; }
        else {
          const int u = (r + k) % 15, w = (r + 15 - k) % 15;
          pk = u < w ? u : w; qk = u < w ? w : u;
        }
        float tp = a[pk], tq = a[qk];
        a[pk] = fmaf(-sk, tq, ck * tp);
        a[qk] = fmaf(sk, tp, ck * tq);
      }
    }
  }
}

// ---------------------------------------------------------------------------
// K1: log_eig(S) -> tril vector [NMAT,136]
// ---------------------------------------------------------------------------
__global__ __launch_bounds__(256) void k1_logvec(const float* __restrict__ S, float* __restrict__ vec) {
  __shared__ float Vld[16][272];   // 16 matrices x (16 cols x stride 17)
  __shared__ float lwld[16][16];
  const int tid = threadIdx.x;
  const int lane = tid & 63;
  const int mloc = tid >> 4;
  const int sub = tid & 15;
  const int mat = blockIdx.x * 16 + mloc;
  float a[16], v[16], diag = 0.f;
  const float* Sp = S + (size_t)mat * 256;
#pragma unroll
  for (int i = 0; i < 16; ++i) {
    a[i] = Sp[i * 16 + sub];
    v[i] = (i == sub) ? 1.f : 0.f;
    if (i == sub) diag = a[i];
  }
  jacobi16_reg(a, v, diag, lane);
  float* Vc = &Vld[mloc][0];
#pragma unroll
  for (int i = 0; i < 16; ++i) Vc[sub * 17 + i] = v[i];   // col sub, row i
  lwld[mloc][sub] = __logf(fmaxf(diag, 1e-8f));
  __syncthreads();
  // logS_{r,c} = sum_j lw_j V[r][j] V[c][j];  V[r][j] = Vc[j*17+r]
  for (int idx = sub; idx < DIMV; idx += 16) {
    int rr = (int)((sqrtf(8.f * (float)idx + 1.f) - 1.f) * 0.5f);
    while ((rr + 1) * (rr + 2) / 2 <= idx) ++rr;
    while (rr * (rr + 1) / 2 > idx) --rr;
    int ccol = idx - rr * (rr + 1) / 2;
    float acc = 0.f;
#pragma unroll
    for (int j = 0; j < 16; ++j)
      acc += lwld[mloc][j] * Vc[j * 17 + rr] * Vc[j * 17 + ccol];
    vec[(size_t)mat * DIMV + idx] = acc;
  }
}

// ---------------------------------------------------------------------------
// K2: QKV projection  Y[16384,408] = X[16384,136] @ W^T + b
// Wave-uniform W indices (L1-resident chunk); one thread per row.
// ---------------------------------------------------------------------------
__global__ __launch_bounds__(256) void k2_qkv(const float* __restrict__ X, const float* __restrict__ W,
                                              const float* __restrict__ bias, float* __restrict__ Y) {
  const int row = blockIdx.x * 256 + threadIdx.x;
  const int n0 = blockIdx.y * 17;
  const float4* __restrict__ x4 = (const float4*)(X + (size_t)row * DIMV);
  const float4* __restrict__ w4 = (const float4*)W;
  float acc[17];
#pragma unroll
  for (int c = 0; c < 17; ++c) acc[c] = bias[n0 + c];
#pragma unroll 2
  for (int k4 = 0; k4 < 34; ++k4) {
    const float4 xv = x4[k4];
#pragma unroll
    for (int c = 0; c < 17; ++c) {
      const float4 wv = w4[(size_t)(n0 + c) * 34 + k4];
      acc[c] = fmaf(xv.x, wv.x, acc[c]);
      acc[c] = fmaf(xv.y, wv.y, acc[c]);
      acc[c] = fmaf(xv.z, wv.z, acc[c]);
      acc[c] = fmaf(xv.w, wv.w, acc[c]);
    }
  }
  float* yp = Y + (size_t)row * QKVD + n0;
#pragma unroll
  for (int c = 0; c < 17; ++c) yp[c] = acc[c];
}

// ---------------------------------------------------------------------------
// K3: attention, head-dim split x2: thread pair (2i,2i+1) owns one q-row;
// each half handles 20 of 40 padded dims; scores combined via shfl_xor(1).
// K/V tiles (32 keys x 40 floats) staged in LDS; broadcast b128 reads.
// ---------------------------------------------------------------------------
__global__ __launch_bounds__(256) void k3_attn(const float* __restrict__ QKV, float* __restrict__ O) {
  __shared__ float Kt[32 * 40];
  __shared__ float Vt[32 * 40];
  const int b = blockIdx.x >> 2;
  const int h = blockIdx.x & 3;
  const int half = threadIdx.x & 1;
  const int row = blockIdx.y * 128 + (threadIdx.x >> 1);
  const float scale = 0.1714985851425088f;  // 1/sqrt(34)
  float q[20], o[20];
  const float* qp = QKV + ((size_t)(b * L_SZ + row)) * QKVD + h * HD;
#pragma unroll
  for (int d = 0; d < 20; ++d) {
    const int dd = half * 20 + d;
    q[d] = (dd < HD) ? qp[dd] * scale : 0.f;
    o[d] = 0.f;
  }
  float m = -1e30f, l = 0.f;

  for (int t = 0; t < 32; ++t) {
    __syncthreads();
    const size_t kbase = ((size_t)(b * L_SZ + t * 32)) * QKVD + h * HD;
    for (int e = threadIdx.x; e < 1280; e += 256) {
      const int kk = e / 40, d = e - kk * 40;
      const bool real = (d < HD);
      Kt[e] = real ? QKV[kbase + (size_t)kk * QKVD + DIMV + d] : 0.f;
      Vt[e] = real ? QKV[kbase + (size_t)kk * QKVD + 2 * DIMV + d] : 0.f;
    }
    __syncthreads();

    float sv[32];
#pragma unroll 8
    for (int kk = 0; kk < 32; ++kk) {
      const float4* kr = (const float4*)&Kt[kk * 40 + half * 20];
      float acc = 0.f;
#pragma unroll
      for (int d4 = 0; d4 < 5; ++d4) {
        const float4 kv = kr[d4];
        acc = fmaf(q[d4*4+0], kv.x, acc);
        acc = fmaf(q[d4*4+1], kv.y, acc);
        acc = fmaf(q[d4*4+2], kv.z, acc);
        acc = fmaf(q[d4*4+3], kv.w, acc);
      }
      sv[kk] = acc + __shfl_xor(acc, 1);
    }
    float tmax = sv[0];
#pragma unroll
    for (int kk = 1; kk < 32; ++kk) tmax = fmaxf(tmax, sv[kk]);
    const float mn = fmaxf(m, tmax);
    const float corr = __expf(m - mn);
    l *= corr;
#pragma unroll
    for (int d = 0; d < 20; ++d) o[d] *= corr;
#pragma unroll 8
    for (int kk = 0; kk < 32; ++kk) {
      const float p = __expf(sv[kk] - mn);
      l += p;
      const float4* vr = (const float4*)&Vt[kk * 40 + half * 20];
#pragma unroll
      for (int d4 = 0; d4 < 5; ++d4) {
        const float4 vv = vr[d4];
        o[d4*4+0] = fmaf(p, vv.x, o[d4*4+0]);
        o[d4*4+1] = fmaf(p, vv.y, o[d4*4+1]);
        o[d4*4+2] = fmaf(p, vv.z, o[d4*4+2]);
        o[d4*4+3] = fmaf(p, vv.w, o[d4*4+3]);
      }
    }
    m = mn;
  }
  const float inv = 1.f / l;
  float* op = O + ((size_t)(b * L_SZ + row)) * DIMV + h * HD;
#pragma unroll
  for (int d = 0; d < 20; ++d) {
    const int dd = half * 20 + d;
    if (dd < HD) op[dd] = o[d] * inv;
  }
}

// ---------------------------------------------------------------------------
// K4: out-projection + residual, wave-uniform W (same structure as K2).
// ---------------------------------------------------------------------------
__global__ __launch_bounds__(256) void k4_outproj(const float* __restrict__ X, const float* __restrict__ W,
                                                  const float* __restrict__ bias, const float* __restrict__ resid,
                                                  float* __restrict__ Y) {
  const int row = blockIdx.x * 256 + threadIdx.x;
  const int n0 = blockIdx.y * 17;
  const float4* __restrict__ x4 = (const float4*)(X + (size_t)row * DIMV);
  const float4* __restrict__ w4 = (const float4*)W;
  float acc[17];
#pragma unroll
  for (int c = 0; c < 17; ++c) acc[c] = bias[n0 + c];
#pragma unroll 2
  for (int k4 = 0; k4 < 34; ++k4) {
    const float4 xv = x4[k4];
#pragma unroll
    for (int c = 0; c < 17; ++c) {
      const float4 wv = w4[(size_t)(n0 + c) * 34 + k4];
      acc[c] = fmaf(xv.x, wv.x, acc[c]);
      acc[c] = fmaf(xv.y, wv.y, acc[c]);
      acc[c] = fmaf(xv.z, wv.z, acc[c]);
      acc[c] = fmaf(xv.w, wv.w, acc[c]);
    }
  }
  const float* rp = resid + (size_t)row * DIMV + n0;
  float* yp = Y + (size_t)row * DIMV + n0;
#pragma unroll
  for (int c = 0; c < 17; ++c) yp[c] = acc[c] + rp[c];
}

// ---------------------------------------------------------------------------
// K5: rebuild symmetric matrix from vec_out, exp_eig, write 16x16 output
// ---------------------------------------------------------------------------
__global__ __launch_bounds__(256) void k5_expm(const float* __restrict__ vecOut, float* __restrict__ out) {
  __shared__ float Vld[16][272];
  __shared__ float eld[16][16];
  const int tid = threadIdx.x;
  const int lane = tid & 63;
  const int mloc = tid >> 4;
  const int sub = tid & 15;
  const int mat = blockIdx.x * 16 + mloc;
  float a[16], v[16], diag = 0.f;
  const float* vp = vecOut + (size_t)mat * DIMV;
#pragma unroll
  for (int i = 0; i < 16; ++i) {
    const int rr = i > sub ? i : sub;
    const int cc = i + sub - rr;
    a[i] = vp[rr * (rr + 1) / 2 + cc];
    v[i] = (i == sub) ? 1.f : 0.f;
    if (i == sub) diag = a[i];
  }
  jacobi16_reg(a, v, diag, lane);
  float* Vc = &Vld[mloc][0];
#pragma unroll
  for (int i = 0; i < 16; ++i) Vc[sub * 17 + i] = v[i];
  eld[mloc][sub] = __expf(diag);
  __syncthreads();
  // O[i][j] = sum_m e_m V[i][m] V[j][m]; this thread computes column j=sub
  float u[16];
#pragma unroll
  for (int j = 0; j < 16; ++j) u[j] = eld[mloc][j] * Vc[j * 17 + sub];
#pragma unroll
  for (int i = 0; i < 16; ++i) {
    float acc = 0.f;
#pragma unroll
    for (int j = 0; j < 16; ++j) acc = fmaf(u[j], Vc[j * 17 + i], acc);
    out[(size_t)mat * 256 + i * 16 + sub] = acc;
  }
}

// ---------------------------------------------------------------------------
extern "C" void kernel_launch(void* const* d_in, const int* in_sizes, int n_in,
                              void* d_out, int out_size, void* d_ws, size_t ws_size,
                              hipStream_t stream) {
  const float* S     = (const float*)d_in[0];
  const float* in_w  = (const float*)d_in[1];
  const float* in_b  = (const float*)d_in[2];
  const float* out_w = (const float*)d_in[3];
  const float* out_b = (const float*)d_in[4];
  float* out = (float*)d_out;
  float* ws = (float*)d_ws;
  // workspace (f32): vec_in[16384*136] | qkv[16384*408] | attn[16384*136] | vec_out[16384*136]
  float* vec_in  = ws;
  float* qkv     = vec_in + (size_t)NMAT * DIMV;
  float* attn    = qkv    + (size_t)NMAT * QKVD;
  float* vec_out = attn   + (size_t)NMAT * DIMV;

  k1_logvec <<<dim3(NMAT / 16),      dim3(256), 0, stream>>>(S, vec_in);
  k2_qkv    <<<dim3(NMAT / 256, 24), dim3(256), 0, stream>>>(vec_in, in_w, in_b, qkv);
  k3_attn   <<<dim3(64, 8),          dim3(256), 0, stream>>>(qkv, attn);
  k4_outproj<<<dim3(NMAT / 256, 8),  dim3(256), 0, stream>>>(attn, out_w, out_b, vec_in, vec_out);
  k5_expm   <<<dim3(NMAT / 16),      dim3(256), 0, stream>>>(vec_out, out);
}

// Round 4
// 742.102 us; speedup vs baseline: 3.1761x; 1.4252x over previous
//
#include <hip/hip_runtime.h>
#include <math.h>

#define B_SZ 16
#define L_SZ 1024
#define NMAT (B_SZ * L_SZ)   // 16384
#define DIMV 136
#define QKVD 408
#define HD 34
#define NH 4
#define NSWEEP 6

typedef __attribute__((ext_vector_type(8))) short short8;
typedef __attribute__((ext_vector_type(16))) float f32x16;
union F8 { short8 s; uint32_t u[4]; };

struct S3 { uint32_t h, m, l; };
// 3-way truncation split of f32 into bf16 parts (stored as f32 with low16=0).
__device__ __forceinline__ S3 split3(float x) {
  S3 r;
  uint32_t xb = __float_as_uint(x);
  r.h = xb & 0xffff0000u;
  float rr = x - __uint_as_float(r.h);
  r.m = __float_as_uint(rr) & 0xffff0000u;
  float r2 = rr - __uint_as_float(r.m);
  r.l = __float_as_uint(r2) & 0xffff0000u;
  return r;
}
// pack two hi16-masked values into one u32 of 2 bf16 (a -> low short)
__device__ __forceinline__ uint32_t pkb(uint32_t a, uint32_t b) { return (a >> 16) | b; }

// ---------------------------------------------------------------------------
// sel16: extract a[j] for runtime j via cndmask tree
// ---------------------------------------------------------------------------
__device__ __forceinline__ float sel16(const float a[16], int j) {
  float p0 = (j & 1) ? a[1] : a[0];
  float p1 = (j & 1) ? a[3] : a[2];
  float p2 = (j & 1) ? a[5] : a[4];
  float p3 = (j & 1) ? a[7] : a[6];
  float p4 = (j & 1) ? a[9] : a[8];
  float p5 = (j & 1) ? a[11] : a[10];
  float p6 = (j & 1) ? a[13] : a[12];
  float p7 = (j & 1) ? a[15] : a[14];
  float q0 = (j & 2) ? p1 : p0;
  float q1 = (j & 2) ? p3 : p2;
  float q2 = (j & 2) ? p5 : p4;
  float q3 = (j & 2) ? p7 : p6;
  float r0 = (j & 4) ? q1 : q0;
  float r1 = (j & 4) ? q3 : q2;
  return (j & 8) ? r1 : r0;
}

// ---------------------------------------------------------------------------
// Register+shuffle parallel cyclic Jacobi (16x16 per 16-lane group).
// ---------------------------------------------------------------------------
__device__ __forceinline__ void jacobi16_reg(float a[16], float v[16], float& diag,
                                             const int lane) {
  const int sub = lane & 15;
  const int gbase = lane & 48;
  for (int sweep = 0; sweep < NSWEEP; ++sweep) {
#pragma unroll
    for (int r = 0; r < 15; ++r) {
      int partner;
      if (sub == 15) partner = r;
      else {
        int d = sub - r; if (d < 0) d += 15;
        if (d == 0) partner = 15;
        else if (d <= 7) { partner = r - d; if (partner < 0) partner += 15; }
        else { partner = r + 15 - d; if (partner >= 15) partner -= 15; }
      }
      const int plane = gbase | partner;
      float oa[16], ov[16];
#pragma unroll
      for (int i = 0; i < 16; ++i) oa[i] = __shfl(a[i], plane);
#pragma unroll
      for (int i = 0; i < 16; ++i) ov[i] = __shfl(v[i], plane);
      const float diag_o = __shfl(diag, plane);
      const bool amP = sub < partner;
      const float app = amP ? diag : diag_o;
      const float aqq = amP ? diag_o : diag;
      const float apq_loc = sel16(a, partner);
      const int pl = gbase | (amP ? sub : partner);
      const float apq = __shfl(apq_loc, pl);
      float c, s;
      {
        float theta = (aqq - app) / (2.f * apq);
        float t = 1.f / (fabsf(theta) + sqrtf(fmaf(theta, theta, 1.f)));
        t = (theta < 0.f) ? -t : t;
        t = (fabsf(apq) < 1e-30f) ? 0.f : t;
        c = rsqrtf(fmaf(t, t, 1.f));
        s = t * c;
      }
      const float sgn = amP ? -s : s;
#pragma unroll
      for (int i = 0; i < 16; ++i) {
        a[i] = fmaf(sgn, oa[i], c * a[i]);
        v[i] = fmaf(sgn, ov[i], c * v[i]);
      }
      const float cc = c * c, ss2 = s * s, cs2 = 2.f * c * s;
      const float dp = fmaf(cc, app, fmaf(ss2, aqq, -cs2 * apq));
      const float dq = fmaf(ss2, app, fmaf(cc, aqq, cs2 * apq));
      diag = amP ? dp : dq;
#pragma unroll
      for (int k = 0; k < 8; ++k) {
        const int owner = (k == 0) ? r : (r + k) % 15;
        float ck = __shfl(c, gbase | owner);
        float sk = __shfl(s, gbase | owner);
        int pk, qk;
        if (k == 0) { pk = r; qk = 15; }
        else {
          const int u = (r + k) % 15, w = (r + 15 - k) % 15;
          pk = u < w ? u : w; qk = u < w ? w : u;
        }
        float tp = a[pk], tq = a[qk];
        a[pk] = fmaf(-sk, tq, ck * tp);
        a[qk] = fmaf(sk, tp, ck * tq);
      }
    }
  }
}

// ---------------------------------------------------------------------------
// K1: log_eig(S) -> tril vector [NMAT,136]
// ---------------------------------------------------------------------------
__global__ __launch_bounds__(256) void k1_logvec(const float* __restrict__ S, float* __restrict__ vec) {
  __shared__ float Vld[16][272];
  __shared__ float lwld[16][16];
  const int tid = threadIdx.x;
  const int lane = tid & 63;
  const int mloc = tid >> 4;
  const int sub = tid & 15;
  const int mat = blockIdx.x * 16 + mloc;
  float a[16], v[16], diag = 0.f;
  const float* Sp = S + (size_t)mat * 256;
#pragma unroll
  for (int i = 0; i < 16; ++i) {
    a[i] = Sp[i * 16 + sub];
    v[i] = (i == sub) ? 1.f : 0.f;
    if (i == sub) diag = a[i];
  }
  jacobi16_reg(a, v, diag, lane);
  float* Vc = &Vld[mloc][0];
#pragma unroll
  for (int i = 0; i < 16; ++i) Vc[sub * 17 + i] = v[i];
  lwld[mloc][sub] = __logf(fmaxf(diag, 1e-8f));
  __syncthreads();
  for (int idx = sub; idx < DIMV; idx += 16) {
    int rr = (int)((sqrtf(8.f * (float)idx + 1.f) - 1.f) * 0.5f);
    while ((rr + 1) * (rr + 2) / 2 <= idx) ++rr;
    while (rr * (rr + 1) / 2 > idx) --rr;
    int ccol = idx - rr * (rr + 1) / 2;
    float acc = 0.f;
#pragma unroll
    for (int j = 0; j < 16; ++j)
      acc += lwld[mloc][j] * Vc[j * 17 + rr] * Vc[j * 17 + ccol];
    vec[(size_t)mat * DIMV + idx] = acc;
  }
}

// ---------------------------------------------------------------------------
// K2: QKV projection; writes qkv in [part(3)][b(16)][h(4)][row(1024)][34] layout
// ---------------------------------------------------------------------------
__global__ __launch_bounds__(256) void k2_qkv(const float* __restrict__ X, const float* __restrict__ W,
                                              const float* __restrict__ bias, float* __restrict__ Y) {
  const int row = blockIdx.x * 256 + threadIdx.x;
  const int n0 = blockIdx.y * 17;
  const float4* __restrict__ x4 = (const float4*)(X + (size_t)row * DIMV);
  const float4* __restrict__ w4 = (const float4*)W;
  float acc[17];
#pragma unroll
  for (int c = 0; c < 17; ++c) acc[c] = bias[n0 + c];
#pragma unroll 2
  for (int k4 = 0; k4 < 34; ++k4) {
    const float4 xv = x4[k4];
#pragma unroll
    for (int c = 0; c < 17; ++c) {
      const float4 wv = w4[(size_t)(n0 + c) * 34 + k4];
      acc[c] = fmaf(xv.x, wv.x, acc[c]);
      acc[c] = fmaf(xv.y, wv.y, acc[c]);
      acc[c] = fmaf(xv.z, wv.z, acc[c]);
      acc[c] = fmaf(xv.w, wv.w, acc[c]);
    }
  }
  const int b = row >> 10, lrow = row & 1023;
#pragma unroll
  for (int c = 0; c < 17; ++c) {
    const int n = n0 + c;
    const int p = n / DIMV, rr = n - p * DIMV;
    const int hh = rr / HD, dd = rr - hh * HD;
    Y[((size_t)((p * B_SZ + b) * NH + hh) * L_SZ + lrow) * HD + dd] = acc[c];
  }
}

// ---------------------------------------------------------------------------
// K3: flash attention via split-bf16x3 MFMA (32x32x16).
// Per block: one (b,h), 128 q-rows (4 waves x 32). Swapped products:
// S^T = K Q^T (q-row lane-local), O^T = V^T P^T.
// ---------------------------------------------------------------------------
__global__ __launch_bounds__(256) void k3_attn(const float* __restrict__ QKV, float* __restrict__ Oout) {
  __shared__ __align__(16) uint32_t Kh[6 * 32 * 4], Km[6 * 32 * 4], Kl[6 * 32 * 4];
  __shared__ __align__(16) uint16_t VTh[4 * 64 * 8], VTm[4 * 64 * 8], VTl[4 * 64 * 8];
  const int tid = threadIdx.x;
  const int lane = tid & 63;
  const int w = tid >> 6;
  const int bh = blockIdx.x;
  const int head = bh & 3;
  const int b = bh >> 2;
  const int qrl = lane & 31;           // q-row within wave / LDS row index
  const int hh = lane >> 5;            // lane half
  const int row = blockIdx.y * 128 + w * 32 + qrl;
  const size_t planeQ = ((size_t)(0 * 64 + bh)) * L_SZ * HD;
  const size_t planeK = ((size_t)(1 * 64 + bh)) * L_SZ * HD;
  const size_t planeV = ((size_t)(2 * 64 + bh)) * L_SZ * HD;
  const float scale = 0.1714985851425088f;  // 1/sqrt(34)

  // zero LDS (covers pad regions; staging only writes real elements)
  for (int i = tid; i < 6 * 32 * 4; i += 256) { Kh[i] = 0; Km[i] = 0; Kl[i] = 0; }
  for (int i = tid; i < 4 * 64 * 8; i += 256) { VTh[i] = 0; VTm[i] = 0; VTl[i] = 0; }

  // Q fragments (B-operand of S^T): lane holds Q[row=qrl][kd = c*16 + hh*8 + e]
  F8 qfh[3], qfm[3], qfl[3];
  const float* qp = QKV + planeQ + (size_t)row * HD;
#pragma unroll
  for (int c = 0; c < 3; ++c) {
#pragma unroll
    for (int e2 = 0; e2 < 4; ++e2) {
      const int kd = c * 16 + hh * 8 + 2 * e2;
      float2 xy = (kd < HD) ? *(const float2*)(qp + kd) : make_float2(0.f, 0.f);
      xy.x *= scale; xy.y *= scale;
      S3 sx = split3(xy.x), sy = split3(xy.y);
      qfh[c].u[e2] = pkb(sx.h, sy.h);
      qfm[c].u[e2] = pkb(sx.m, sy.m);
      qfl[c].u[e2] = pkb(sx.l, sy.l);
    }
  }

  f32x16 o0, o1;
#pragma unroll
  for (int i = 0; i < 16; ++i) { o0[i] = 0.f; o1[i] = 0.f; }
  float mrun = -3.0e38f, lsum = 0.f;

  for (int t = 0; t < 32; ++t) {
    __syncthreads();   // prior MFMA reads done before overwrite
    // ---- stage K,V tile (32 keys x 34) as bf16x3 in frag-native layouts ----
    for (int u = tid; u < 1088; u += 256) {
      const bool isK = u < 544;
      const int e = isK ? u : u - 544;
      const int key = e / 17;
      const int j = e - key * 17;      // kd pair (2j, 2j+1)
      const float2 xy = *(const float2*)(QKV + (isK ? planeK : planeV) +
                                         ((size_t)(t * 32 + key)) * HD + 2 * j);
      const S3 sx = split3(xy.x), sy = split3(xy.y);
      if (isK) {
        const int di = ((j >> 2) * 32 + key) * 4 + (j & 3);
        Kh[di] = pkb(sx.h, sy.h); Km[di] = pkb(sx.m, sy.m); Kl[di] = pkb(sx.l, sy.l);
      } else {
        const int b0 = ((key >> 3) * 64 + 2 * j) * 8 + (key & 7);
        VTh[b0] = (uint16_t)(sx.h >> 16); VTm[b0] = (uint16_t)(sx.m >> 16); VTl[b0] = (uint16_t)(sx.l >> 16);
        VTh[b0 + 8] = (uint16_t)(sy.h >> 16); VTm[b0 + 8] = (uint16_t)(sy.m >> 16); VTl[b0 + 8] = (uint16_t)(sy.l >> 16);
      }
    }
    __syncthreads();

    // ---- S^T = K Q^T (bf16x3: 6 passes per 16-chunk) ----
    f32x16 s;
#pragma unroll
    for (int i = 0; i < 16; ++i) s[i] = 0.f;
#pragma unroll
    for (int c = 0; c < 3; ++c) {
      F8 ah, am, al;
      const int kidx = ((c * 2 + hh) * 32 + qrl) * 4;
      ah.s = *(const short8*)&Kh[kidx];
      am.s = *(const short8*)&Km[kidx];
      al.s = *(const short8*)&Kl[kidx];
      s = __builtin_amdgcn_mfma_f32_32x32x16_bf16(ah.s, qfh[c].s, s, 0, 0, 0);
      s = __builtin_amdgcn_mfma_f32_32x32x16_bf16(ah.s, qfm[c].s, s, 0, 0, 0);
      s = __builtin_amdgcn_mfma_f32_32x32x16_bf16(am.s, qfh[c].s, s, 0, 0, 0);
      s = __builtin_amdgcn_mfma_f32_32x32x16_bf16(ah.s, qfl[c].s, s, 0, 0, 0);
      s = __builtin_amdgcn_mfma_f32_32x32x16_bf16(am.s, qfm[c].s, s, 0, 0, 0);
      s = __builtin_amdgcn_mfma_f32_32x32x16_bf16(al.s, qfh[c].s, s, 0, 0, 0);
    }

    // ---- online softmax (q-row lane-local; halves synced via shfl_xor 32) ----
    float mymax = s[0];
#pragma unroll
    for (int e = 1; e < 16; ++e) mymax = fmaxf(mymax, s[e]);
    const float pmax = fmaxf(mymax, __shfl_xor(mymax, 32));
    const float mn = fmaxf(mrun, pmax);
    const float corr = __expf(mrun - mn);
    mrun = mn;
    float p[16]; float ps = 0.f;
#pragma unroll
    for (int e = 0; e < 16; ++e) { p[e] = __expf(s[e] - mn); ps += p[e]; }
    ps += __shfl_xor(ps, 32);
    lsum = lsum * corr + ps;
    o0 *= corr; o1 *= corr;

    // ---- split P to bf16x3, pack pairs, exchange halves, build B-frags ----
    uint32_t uo[3][8], po[3][8];
#pragma unroll
    for (int g = 0; g < 8; ++g) {
      const S3 s0 = split3(p[2 * g]), s1 = split3(p[2 * g + 1]);
      uo[0][g] = pkb(s0.h, s1.h); uo[1][g] = pkb(s0.m, s1.m); uo[2][g] = pkb(s0.l, s1.l);
    }
#pragma unroll
    for (int sp = 0; sp < 3; ++sp)
#pragma unroll
      for (int g = 0; g < 8; ++g) po[sp][g] = (uint32_t)__shfl_xor((int)uo[sp][g], 32);
    F8 pf[3][2];
#pragma unroll
    for (int sp = 0; sp < 3; ++sp) {
      pf[sp][0].u[0] = hh ? po[sp][2] : uo[sp][0];
      pf[sp][0].u[1] = hh ? po[sp][3] : uo[sp][1];
      pf[sp][0].u[2] = hh ? uo[sp][2] : po[sp][0];
      pf[sp][0].u[3] = hh ? uo[sp][3] : po[sp][1];
      pf[sp][1].u[0] = hh ? po[sp][6] : uo[sp][4];
      pf[sp][1].u[1] = hh ? po[sp][7] : uo[sp][5];
      pf[sp][1].u[2] = hh ? uo[sp][6] : po[sp][4];
      pf[sp][1].u[3] = hh ? uo[sp][7] : po[sp][5];
    }

    // ---- O^T += V^T P^T (bf16x3) ----
#pragma unroll
    for (int dt = 0; dt < 2; ++dt) {
#pragma unroll
      for (int kc = 0; kc < 2; ++kc) {
        const int vb = ((kc * 2 + hh) * 64 + dt * 32 + qrl) * 8;
        F8 vh2, vm2, vl2;
        vh2.s = *(const short8*)&VTh[vb];
        vm2.s = *(const short8*)&VTm[vb];
        vl2.s = *(const short8*)&VTl[vb];
        f32x16 oa = dt ? o1 : o0;
        oa = __builtin_amdgcn_mfma_f32_32x32x16_bf16(vh2.s, pf[0][kc].s, oa, 0, 0, 0);
        oa = __builtin_amdgcn_mfma_f32_32x32x16_bf16(vh2.s, pf[1][kc].s, oa, 0, 0, 0);
        oa = __builtin_amdgcn_mfma_f32_32x32x16_bf16(vm2.s, pf[0][kc].s, oa, 0, 0, 0);
        oa = __builtin_amdgcn_mfma_f32_32x32x16_bf16(vh2.s, pf[2][kc].s, oa, 0, 0, 0);
        oa = __builtin_amdgcn_mfma_f32_32x32x16_bf16(vm2.s, pf[1][kc].s, oa, 0, 0, 0);
        oa = __builtin_amdgcn_mfma_f32_32x32x16_bf16(vl2.s, pf[0][kc].s, oa, 0, 0, 0);
        if (dt) o1 = oa; else o0 = oa;
      }
    }
  }

  // ---- epilogue: divide by lsum, write q-row (d in per-reg quads) ----
  const float inv = 1.f / lsum;
  float* op = Oout + ((size_t)(b * L_SZ) + row) * DIMV + head * HD;
#pragma unroll
  for (int dt = 0; dt < 2; ++dt) {
#pragma unroll
    for (int rq = 0; rq < 4; ++rq) {
      const int d0 = dt * 32 + 8 * rq + 4 * hh;
      if (d0 < HD) {
        const float a0 = (dt ? o1[rq * 4 + 0] : o0[rq * 4 + 0]) * inv;
        const float a1 = (dt ? o1[rq * 4 + 1] : o0[rq * 4 + 1]) * inv;
        *(float2*)(op + d0) = make_float2(a0, a1);
        if (d0 + 2 < HD) {
          const float a2 = (dt ? o1[rq * 4 + 2] : o0[rq * 4 + 2]) * inv;
          const float a3 = (dt ? o1[rq * 4 + 3] : o0[rq * 4 + 3]) * inv;
          *(float2*)(op + d0 + 2) = make_float2(a2, a3);
        }
      }
    }
  }
}

// ---------------------------------------------------------------------------
// K4: out-projection + residual (wave-uniform W)
// ---------------------------------------------------------------------------
__global__ __launch_bounds__(256) void k4_outproj(const float* __restrict__ X, const float* __restrict__ W,
                                                  const float* __restrict__ bias, const float* __restrict__ resid,
                                                  float* __restrict__ Y) {
  const int row = blockIdx.x * 256 + threadIdx.x;
  const int n0 = blockIdx.y * 17;
  const float4* __restrict__ x4 = (const float4*)(X + (size_t)row * DIMV);
  const float4* __restrict__ w4 = (const float4*)W;
  float acc[17];
#pragma unroll
  for (int c = 0; c < 17; ++c) acc[c] = bias[n0 + c];
#pragma unroll 2
  for (int k4 = 0; k4 < 34; ++k4) {
    const float4 xv = x4[k4];
#pragma unroll
    for (int c = 0; c < 17; ++c) {
      const float4 wv = w4[(size_t)(n0 + c) * 34 + k4];
      acc[c] = fmaf(xv.x, wv.x, acc[c]);
      acc[c] = fmaf(xv.y, wv.y, acc[c]);
      acc[c] = fmaf(xv.z, wv.z, acc[c]);
      acc[c] = fmaf(xv.w, wv.w, acc[c]);
    }
  }
  const float* rp = resid + (size_t)row * DIMV + n0;
  float* yp = Y + (size_t)row * DIMV + n0;
#pragma unroll
  for (int c = 0; c < 17; ++c) yp[c] = acc[c] + rp[c];
}

// ---------------------------------------------------------------------------
// K5: rebuild symmetric matrix, exp_eig, write 16x16 output
// ---------------------------------------------------------------------------
__global__ __launch_bounds__(256) void k5_expm(const float* __restrict__ vecOut, float* __restrict__ out) {
  __shared__ float Vld[16][272];
  __shared__ float eld[16][16];
  const int tid = threadIdx.x;
  const int lane = tid & 63;
  const int mloc = tid >> 4;
  const int sub = tid & 15;
  const int mat = blockIdx.x * 16 + mloc;
  float a[16], v[16], diag = 0.f;
  const float* vp = vecOut + (size_t)mat * DIMV;
#pragma unroll
  for (int i = 0; i < 16; ++i) {
    const int rr = i > sub ? i : sub;
    const int cc = i + sub - rr;
    a[i] = vp[rr * (rr + 1) / 2 + cc];
    v[i] = (i == sub) ? 1.f : 0.f;
    if (i == sub) diag = a[i];
  }
  jacobi16_reg(a, v, diag, lane);
  float* Vc = &Vld[mloc][0];
#pragma unroll
  for (int i = 0; i < 16; ++i) Vc[sub * 17 + i] = v[i];
  eld[mloc][sub] = __expf(diag);
  __syncthreads();
  float u[16];
#pragma unroll
  for (int j = 0; j < 16; ++j) u[j] = eld[mloc][j] * Vc[j * 17 + sub];
#pragma unroll
  for (int i = 0; i < 16; ++i) {
    float acc = 0.f;
#pragma unroll
    for (int j = 0; j < 16; ++j) acc = fmaf(u[j], Vc[j * 17 + i], acc);
    out[(size_t)mat * 256 + i * 16 + sub] = acc;
  }
}

// ---------------------------------------------------------------------------
extern "C" void kernel_launch(void* const* d_in, const int* in_sizes, int n_in,
                              void* d_out, int out_size, void* d_ws, size_t ws_size,
                              hipStream_t stream) {
  const float* S     = (const float*)d_in[0];
  const float* in_w  = (const float*)d_in[1];
  const float* in_b  = (const float*)d_in[2];
  const float* out_w = (const float*)d_in[3];
  const float* out_b = (const float*)d_in[4];
  float* out = (float*)d_out;
  float* ws = (float*)d_ws;
  // workspace (f32): vec_in[16384*136] | qkv[3][16][4][1024][34] | attn[16384*136] | vec_out[16384*136]
  float* vec_in  = ws;
  float* qkv     = vec_in + (size_t)NMAT * DIMV;
  float* attn    = qkv    + (size_t)NMAT * QKVD;
  float* vec_out = attn   + (size_t)NMAT * DIMV;

  k1_logvec <<<dim3(NMAT / 16),      dim3(256), 0, stream>>>(S, vec_in);
  k2_qkv    <<<dim3(NMAT / 256, 24), dim3(256), 0, stream>>>(vec_in, in_w, in_b, qkv);
  k3_attn   <<<dim3(64, 8),          dim3(256), 0, stream>>>(qkv, attn);
  k4_outproj<<<dim3(NMAT / 256, 8),  dim3(256), 0, stream>>>(attn, out_w, out_b, vec_in, vec_out);
  k5_expm   <<<dim3(NMAT / 16),      dim3(256), 0, stream>>>(vec_out, out);
}

// Round 6
// 670.926 us; speedup vs baseline: 3.5131x; 1.1061x over previous
//
#include <hip/hip_runtime.h>
#include <math.h>

#define B_SZ 16
#define L_SZ 1024
#define NMAT (B_SZ * L_SZ)   // 16384
#define DIMV 136
#define QKVD 408
#define HD 34
#define NH 4
#define NSWEEP 5

typedef __attribute__((ext_vector_type(8))) short short8;
typedef __attribute__((ext_vector_type(16))) float f32x16;
union F8 { short8 s; uint32_t u[4]; };

struct S3 { uint32_t h, m, l; };
// 3-way truncation split of f32 into bf16 parts (stored as f32 with low16=0).
__device__ __forceinline__ S3 split3(float x) {
  S3 r;
  uint32_t xb = __float_as_uint(x);
  r.h = xb & 0xffff0000u;
  float rr = x - __uint_as_float(r.h);
  r.m = __float_as_uint(rr) & 0xffff0000u;
  float r2 = rr - __uint_as_float(r.m);
  r.l = __float_as_uint(r2) & 0xffff0000u;
  return r;
}
// pack two hi16-masked values into one u32 of 2 bf16 (a -> low short)
__device__ __forceinline__ uint32_t pkb(uint32_t a, uint32_t b) { return (a >> 16) | b; }

// ---------------------------------------------------------------------------
// sel16: extract a[j] for runtime j via cndmask tree
// ---------------------------------------------------------------------------
__device__ __forceinline__ float sel16(const float a[16], int j) {
  float p0 = (j & 1) ? a[1] : a[0];
  float p1 = (j & 1) ? a[3] : a[2];
  float p2 = (j & 1) ? a[5] : a[4];
  float p3 = (j & 1) ? a[7] : a[6];
  float p4 = (j & 1) ? a[9] : a[8];
  float p5 = (j & 1) ? a[11] : a[10];
  float p6 = (j & 1) ? a[13] : a[12];
  float p7 = (j & 1) ? a[15] : a[14];
  float q0 = (j & 2) ? p1 : p0;
  float q1 = (j & 2) ? p3 : p2;
  float q2 = (j & 2) ? p5 : p4;
  float q3 = (j & 2) ? p7 : p6;
  float r0 = (j & 4) ? q1 : q0;
  float r1 = (j & 4) ? q3 : q2;
  return (j & 8) ? r1 : r0;
}

// ---------------------------------------------------------------------------
// Register+shuffle parallel cyclic Jacobi (16x16 per 16-lane group).
// DS ops/round: 16 (a-cols) + 16 (v-cols) + 1 (diag) + 1 (apq) + 8 (t bcast)
// = 42; c,s recomputed per-lane from t (deterministic -> bit-identical).
// ---------------------------------------------------------------------------
__device__ __forceinline__ void jacobi16_reg(float a[16], float v[16], float& diag,
                                             const int lane) {
  const int sub = lane & 15;
  const int gbase = lane & 48;
  for (int sweep = 0; sweep < NSWEEP; ++sweep) {
#pragma unroll
    for (int r = 0; r < 15; ++r) {
      int partner;
      if (sub == 15) partner = r;
      else {
        int d = sub - r; if (d < 0) d += 15;
        if (d == 0) partner = 15;
        else if (d <= 7) { partner = r - d; if (partner < 0) partner += 15; }
        else { partner = r + 15 - d; if (partner >= 15) partner -= 15; }
      }
      const int plane = gbase | partner;
      float oa[16], ov[16];
#pragma unroll
      for (int i = 0; i < 16; ++i) oa[i] = __shfl(a[i], plane);
#pragma unroll
      for (int i = 0; i < 16; ++i) ov[i] = __shfl(v[i], plane);
      const float diag_o = __shfl(diag, plane);
      const bool amP = sub < partner;
      const float app = amP ? diag : diag_o;
      const float aqq = amP ? diag_o : diag;
      const float apq_loc = sel16(a, partner);
      const int pl = gbase | (amP ? sub : partner);
      const float apq = __shfl(apq_loc, pl);
      float c, s, t;
      {
        float theta = (aqq - app) / (2.f * apq);
        float tt = 1.f / (fabsf(theta) + sqrtf(fmaf(theta, theta, 1.f)));
        tt = (theta < 0.f) ? -tt : tt;
        t = (fabsf(apq) < 1e-30f) ? 0.f : tt;
        c = rsqrtf(fmaf(t, t, 1.f));
        s = t * c;
      }
      const float sgn = amP ? -s : s;
#pragma unroll
      for (int i = 0; i < 16; ++i) {
        a[i] = fmaf(sgn, oa[i], c * a[i]);
        v[i] = fmaf(sgn, ov[i], c * v[i]);
      }
      const float cc = c * c, ss2 = s * s, cs2 = 2.f * c * s;
      const float dp = fmaf(cc, app, fmaf(ss2, aqq, -cs2 * apq));
      const float dq = fmaf(ss2, app, fmaf(cc, aqq, cs2 * apq));
      diag = amP ? dp : dq;
#pragma unroll
      for (int k = 0; k < 8; ++k) {
        const int owner = (k == 0) ? r : (r + k) % 15;
        const float tk = __shfl(t, gbase | owner);
        const float ck = rsqrtf(fmaf(tk, tk, 1.f));
        const float sk = tk * ck;
        int pk, qk;
        if (k == 0) { pk = r; qk = 15; }
        else {
          const int u = (r + k) % 15, w = (r + 15 - k) % 15;
          pk = u < w ? u : w; qk = u < w ? w : u;
        }
        float tp = a[pk], tq = a[qk];
        a[pk] = fmaf(-sk, tq, ck * tp);
        a[qk] = fmaf(sk, tp, ck * tq);
      }
    }
  }
}

// ---------------------------------------------------------------------------
// K1: log_eig(S) -> tril vector [NMAT,136]
// ---------------------------------------------------------------------------
__global__ __launch_bounds__(256) void k1_logvec(const float* __restrict__ S, float* __restrict__ vec) {
  __shared__ float Vld[16][272];
  __shared__ float lwld[16][16];
  const int tid = threadIdx.x;
  const int lane = tid & 63;
  const int mloc = tid >> 4;
  const int sub = tid & 15;
  const int mat = blockIdx.x * 16 + mloc;
  float a[16], v[16], diag = 0.f;
  const float* Sp = S + (size_t)mat * 256;
#pragma unroll
  for (int i = 0; i < 16; ++i) {
    a[i] = Sp[i * 16 + sub];
    v[i] = (i == sub) ? 1.f : 0.f;
    if (i == sub) diag = a[i];
  }
  jacobi16_reg(a, v, diag, lane);
  float* Vc = &Vld[mloc][0];
#pragma unroll
  for (int i = 0; i < 16; ++i) Vc[sub * 17 + i] = v[i];
  lwld[mloc][sub] = __logf(fmaxf(diag, 1e-8f));
  __syncthreads();
  for (int idx = sub; idx < DIMV; idx += 16) {
    int rr = (int)((sqrtf(8.f * (float)idx + 1.f) - 1.f) * 0.5f);
    while ((rr + 1) * (rr + 2) / 2 <= idx) ++rr;
    while (rr * (rr + 1) / 2 > idx) --rr;
    int ccol = idx - rr * (rr + 1) / 2;
    float acc = 0.f;
#pragma unroll
    for (int j = 0; j < 16; ++j)
      acc += lwld[mloc][j] * Vc[j * 17 + rr] * Vc[j * 17 + ccol];
    vec[(size_t)mat * DIMV + idx] = acc;
  }
}

// ---------------------------------------------------------------------------
// K2: QKV projection; writes qkv DIM-MAJOR: [part(3)][b*4+h(64)][dim(34)][row(1024)]
// so stores are coalesced (consecutive threads = consecutive rows).
// ---------------------------------------------------------------------------
__global__ __launch_bounds__(256) void k2_qkv(const float* __restrict__ X, const float* __restrict__ W,
                                              const float* __restrict__ bias, float* __restrict__ Y) {
  const int row = blockIdx.x * 256 + threadIdx.x;
  const int n0 = blockIdx.y * 17;
  const float4* __restrict__ x4 = (const float4*)(X + (size_t)row * DIMV);
  const float4* __restrict__ w4 = (const float4*)W;
  float acc[17];
#pragma unroll
  for (int c = 0; c < 17; ++c) acc[c] = bias[n0 + c];
#pragma unroll 2
  for (int k4 = 0; k4 < 34; ++k4) {
    const float4 xv = x4[k4];
#pragma unroll
    for (int c = 0; c < 17; ++c) {
      const float4 wv = w4[(size_t)(n0 + c) * 34 + k4];
      acc[c] = fmaf(xv.x, wv.x, acc[c]);
      acc[c] = fmaf(xv.y, wv.y, acc[c]);
      acc[c] = fmaf(xv.z, wv.z, acc[c]);
      acc[c] = fmaf(xv.w, wv.w, acc[c]);
    }
  }
  const int b = row >> 10, lrow = row & 1023;
#pragma unroll
  for (int c = 0; c < 17; ++c) {
    const int n = n0 + c;
    const int p = n / DIMV, rr = n - p * DIMV;
    const int hh = rr / HD, dd = rr - hh * HD;
    Y[(((size_t)(p * 64 + b * NH + hh)) * HD + dd) * L_SZ + lrow] = acc[c];
  }
}

// ---------------------------------------------------------------------------
// K3: flash attention via split-bf16x3 MFMA (32x32x16).
// QKV is dim-major [part][bh][dim][row]. Per block: one (b,h), 128 q-rows.
// S^T = K Q^T (q-row lane-local), O^T = V^T P^T.
// ---------------------------------------------------------------------------
__global__ __launch_bounds__(256) void k3_attn(const float* __restrict__ QKV, float* __restrict__ Oout) {
  __shared__ __align__(16) uint32_t Kh[6 * 32 * 4], Km[6 * 32 * 4], Kl[6 * 32 * 4];
  __shared__ __align__(16) uint16_t VTh[4 * 64 * 8], VTm[4 * 64 * 8], VTl[4 * 64 * 8];
  const int tid = threadIdx.x;
  const int lane = tid & 63;
  const int w = tid >> 6;
  const int bh = blockIdx.x;
  const int head = bh & 3;
  const int b = bh >> 2;
  const int qrl = lane & 31;           // q-row within wave / LDS row index
  const int hh = lane >> 5;            // lane half
  const int row = blockIdx.y * 128 + w * 32 + qrl;
  const float* __restrict__ Qp = QKV + ((size_t)(0 * 64 + bh)) * HD * L_SZ;
  const float* __restrict__ Kp = QKV + ((size_t)(1 * 64 + bh)) * HD * L_SZ;
  const float* __restrict__ Vp = QKV + ((size_t)(2 * 64 + bh)) * HD * L_SZ;
  const float scale = 0.1714985851425088f;  // 1/sqrt(34)

  // zero LDS (covers pad regions; staging only writes real elements)
  for (int i = tid; i < 6 * 32 * 4; i += 256) { Kh[i] = 0; Km[i] = 0; Kl[i] = 0; }
  for (int i = tid; i < 4 * 64 * 8; i += 256) { VTh[i] = 0; VTm[i] = 0; VTl[i] = 0; }

  // Q fragments (B-operand of S^T): lane holds Q[row=qrl][kd = c*16 + hh*8 + e]
  F8 qfh[3], qfm[3], qfl[3];
#pragma unroll
  for (int c = 0; c < 3; ++c) {
#pragma unroll
    for (int e2 = 0; e2 < 4; ++e2) {
      const int kd = c * 16 + hh * 8 + 2 * e2;
      float x = 0.f, y = 0.f;
      if (kd < HD) {           // kd even; kd<HD implies kd+1<HD (HD even)
        x = Qp[(size_t)kd * L_SZ + row] * scale;
        y = Qp[(size_t)(kd + 1) * L_SZ + row] * scale;
      }
      S3 sx = split3(x), sy = split3(y);
      qfh[c].u[e2] = pkb(sx.h, sy.h);
      qfm[c].u[e2] = pkb(sx.m, sy.m);
      qfl[c].u[e2] = pkb(sx.l, sy.l);
    }
  }

  f32x16 o0, o1;
#pragma unroll
  for (int i = 0; i < 16; ++i) { o0[i] = 0.f; o1[i] = 0.f; }
  float mrun = -3.0e38f, lsum = 0.f;

  for (int t = 0; t < 32; ++t) {
    __syncthreads();   // prior MFMA reads done before overwrite
    // ---- stage K,V tile (32 keys x 34 dims) as bf16x3 in frag-native layouts ----
    for (int u = tid; u < 1088; u += 256) {
      const bool isK = u < 544;
      const int e = isK ? u : u - 544;
      const int key = e & 31;
      const int j = e >> 5;            // dim pair (2j, 2j+1), j in [0,17)
      const float* __restrict__ P = isK ? Kp : Vp;
      const size_t base = (size_t)(t * 32 + key);
      const float x = P[(size_t)(2 * j) * L_SZ + base];
      const float y = P[(size_t)(2 * j + 1) * L_SZ + base];
      const S3 sx = split3(x), sy = split3(y);
      if (isK) {
        const int di = ((j >> 2) * 32 + key) * 4 + (j & 3);
        Kh[di] = pkb(sx.h, sy.h); Km[di] = pkb(sx.m, sy.m); Kl[di] = pkb(sx.l, sy.l);
      } else {
        const int b0 = ((key >> 3) * 64 + 2 * j) * 8 + (key & 7);
        VTh[b0] = (uint16_t)(sx.h >> 16); VTm[b0] = (uint16_t)(sx.m >> 16); VTl[b0] = (uint16_t)(sx.l >> 16);
        VTh[b0 + 8] = (uint16_t)(sy.h >> 16); VTm[b0 + 8] = (uint16_t)(sy.m >> 16); VTl[b0 + 8] = (uint16_t)(sy.l >> 16);
      }
    }
    __syncthreads();

    // ---- S^T = K Q^T (bf16x3: 6 passes per 16-chunk) ----
    f32x16 s;
#pragma unroll
    for (int i = 0; i < 16; ++i) s[i] = 0.f;
#pragma unroll
    for (int c = 0; c < 3; ++c) {
      F8 ah, am, al;
      const int kidx = ((c * 2 + hh) * 32 + qrl) * 4;
      ah.s = *(const short8*)&Kh[kidx];
      am.s = *(const short8*)&Km[kidx];
      al.s = *(const short8*)&Kl[kidx];
      s = __builtin_amdgcn_mfma_f32_32x32x16_bf16(ah.s, qfh[c].s, s, 0, 0, 0);
      s = __builtin_amdgcn_mfma_f32_32x32x16_bf16(ah.s, qfm[c].s, s, 0, 0, 0);
      s = __builtin_amdgcn_mfma_f32_32x32x16_bf16(am.s, qfh[c].s, s, 0, 0, 0);
      s = __builtin_amdgcn_mfma_f32_32x32x16_bf16(ah.s, qfl[c].s, s, 0, 0, 0);
      s = __builtin_amdgcn_mfma_f32_32x32x16_bf16(am.s, qfm[c].s, s, 0, 0, 0);
      s = __builtin_amdgcn_mfma_f32_32x32x16_bf16(al.s, qfh[c].s, s, 0, 0, 0);
    }

    // ---- online softmax (q-row lane-local; halves synced via shfl_xor 32) ----
    float mymax = s[0];
#pragma unroll
    for (int e = 1; e < 16; ++e) mymax = fmaxf(mymax, s[e]);
    const float pmax = fmaxf(mymax, __shfl_xor(mymax, 32));
    const float mn = fmaxf(mrun, pmax);
    const float corr = __expf(mrun - mn);
    mrun = mn;
    float p[16]; float ps = 0.f;
#pragma unroll
    for (int e = 0; e < 16; ++e) { p[e] = __expf(s[e] - mn); ps += p[e]; }
    ps += __shfl_xor(ps, 32);
    lsum = lsum * corr + ps;
    o0 *= corr; o1 *= corr;

    // ---- split P to bf16x3, pack pairs, exchange halves, build B-frags ----
    uint32_t uo[3][8], po[3][8];
#pragma unroll
    for (int g = 0; g < 8; ++g) {
      const S3 s0 = split3(p[2 * g]), s1 = split3(p[2 * g + 1]);
      uo[0][g] = pkb(s0.h, s1.h); uo[1][g] = pkb(s0.m, s1.m); uo[2][g] = pkb(s0.l, s1.l);
    }
#pragma unroll
    for (int sp = 0; sp < 3; ++sp)
#pragma unroll
      for (int g = 0; g < 8; ++g) po[sp][g] = (uint32_t)__shfl_xor((int)uo[sp][g], 32);
    F8 pf[3][2];
#pragma unroll
    for (int sp = 0; sp < 3; ++sp) {
      pf[sp][0].u[0] = hh ? po[sp][2] : uo[sp][0];
      pf[sp][0].u[1] = hh ? po[sp][3] : uo[sp][1];
      pf[sp][0].u[2] = hh ? uo[sp][2] : po[sp][0];
      pf[sp][0].u[3] = hh ? uo[sp][3] : po[sp][1];
      pf[sp][1].u[0] = hh ? po[sp][6] : uo[sp][4];
      pf[sp][1].u[1] = hh ? po[sp][7] : uo[sp][5];
      pf[sp][1].u[2] = hh ? uo[sp][6] : po[sp][4];
      pf[sp][1].u[3] = hh ? uo[sp][7] : po[sp][5];
    }

    // ---- O^T += V^T P^T (bf16x3) ----
#pragma unroll
    for (int dt = 0; dt < 2; ++dt) {
#pragma unroll
      for (int kc = 0; kc < 2; ++kc) {
        const int vb = ((kc * 2 + hh) * 64 + dt * 32 + qrl) * 8;
        F8 vh2, vm2, vl2;
        vh2.s = *(const short8*)&VTh[vb];
        vm2.s = *(const short8*)&VTm[vb];
        vl2.s = *(const short8*)&VTl[vb];
        f32x16 oa = dt ? o1 : o0;
        oa = __builtin_amdgcn_mfma_f32_32x32x16_bf16(vh2.s, pf[0][kc].s, oa, 0, 0, 0);
        oa = __builtin_amdgcn_mfma_f32_32x32x16_bf16(vh2.s, pf[1][kc].s, oa, 0, 0, 0);
        oa = __builtin_amdgcn_mfma_f32_32x32x16_bf16(vm2.s, pf[0][kc].s, oa, 0, 0, 0);
        oa = __builtin_amdgcn_mfma_f32_32x32x16_bf16(vh2.s, pf[2][kc].s, oa, 0, 0, 0);
        oa = __builtin_amdgcn_mfma_f32_32x32x16_bf16(vm2.s, pf[1][kc].s, oa, 0, 0, 0);
        oa = __builtin_amdgcn_mfma_f32_32x32x16_bf16(vl2.s, pf[0][kc].s, oa, 0, 0, 0);
        if (dt) o1 = oa; else o0 = oa;
      }
    }
  }

  // ---- epilogue: divide by lsum, write q-row (d in per-reg quads) ----
  const float inv = 1.f / lsum;
  float* op = Oout + ((size_t)(b * L_SZ) + row) * DIMV + head * HD;
#pragma unroll
  for (int dt = 0; dt < 2; ++dt) {
#pragma unroll
    for (int rq = 0; rq < 4; ++rq) {
      const int d0 = dt * 32 + 8 * rq + 4 * hh;
      if (d0 < HD) {
        const float a0 = (dt ? o1[rq * 4 + 0] : o0[rq * 4 + 0]) * inv;
        const float a1 = (dt ? o1[rq * 4 + 1] : o0[rq * 4 + 1]) * inv;
        *(float2*)(op + d0) = make_float2(a0, a1);
        if (d0 + 2 < HD) {
          const float a2 = (dt ? o1[rq * 4 + 2] : o0[rq * 4 + 2]) * inv;
          const float a3 = (dt ? o1[rq * 4 + 3] : o0[rq * 4 + 3]) * inv;
          *(float2*)(op + d0 + 2) = make_float2(a2, a3);
        }
      }
    }
  }
}

// ---------------------------------------------------------------------------
// K4: out-projection + residual (wave-uniform W)
// ---------------------------------------------------------------------------
__global__ __launch_bounds__(256) void k4_outproj(const float* __restrict__ X, const float* __restrict__ W,
                                                  const float* __restrict__ bias, const float* __restrict__ resid,
                                                  float* __restrict__ Y) {
  const int row = blockIdx.x * 256 + threadIdx.x;
  const int n0 = blockIdx.y * 17;
  const float4* __restrict__ x4 = (const float4*)(X + (size_t)row * DIMV);
  const float4* __restrict__ w4 = (const float4*)W;
  float acc[17];
#pragma unroll
  for (int c = 0; c < 17; ++c) acc[c] = bias[n0 + c];
#pragma unroll 2
  for (int k4 = 0; k4 < 34; ++k4) {
    const float4 xv = x4[k4];
#pragma unroll
    for (int c = 0; c < 17; ++c) {
      const float4 wv = w4[(size_t)(n0 + c) * 34 + k4];
      acc[c] = fmaf(xv.x, wv.x, acc[c]);
      acc[c] = fmaf(xv.y, wv.y, acc[c]);
      acc[c] = fmaf(xv.z, wv.z, acc[c]);
      acc[c] = fmaf(xv.w, wv.w, acc[c]);
    }
  }
  const float* rp = resid + (size_t)row * DIMV + n0;
  float* yp = Y + (size_t)row * DIMV + n0;
#pragma unroll
  for (int c = 0; c < 17; ++c) yp[c] = acc[c] + rp[c];
}

// ---------------------------------------------------------------------------
// K5: rebuild symmetric matrix, exp_eig, write 16x16 output
// ---------------------------------------------------------------------------
__global__ __launch_bounds__(256) void k5_expm(const float* __restrict__ vecOut, float* __restrict__ out) {
  __shared__ float Vld[16][272];
  __shared__ float eld[16][16];
  const int tid = threadIdx.x;
  const int lane = tid & 63;
  const int mloc = tid >> 4;
  const int sub = tid & 15;
  const int mat = blockIdx.x * 16 + mloc;
  float a[16], v[16], diag = 0.f;
  const float* vp = vecOut + (size_t)mat * DIMV;
#pragma unroll
  for (int i = 0; i < 16; ++i) {
    const int rr = i > sub ? i : sub;
    const int cc = i + sub - rr;
    a[i] = vp[rr * (rr + 1) / 2 + cc];
    v[i] = (i == sub) ? 1.f : 0.f;
    if (i == sub) diag = a[i];
  }
  jacobi16_reg(a, v, diag, lane);
  float* Vc = &Vld[mloc][0];
#pragma unroll
  for (int i = 0; i < 16; ++i) Vc[sub * 17 + i] = v[i];
  eld[mloc][sub] = __expf(diag);
  __syncthreads();
  float u[16];
#pragma unroll
  for (int j = 0; j < 16; ++j) u[j] = eld[mloc][j] * Vc[j * 17 + sub];
#pragma unroll
  for (int i = 0; i < 16; ++i) {
    float acc = 0.f;
#pragma unroll
    for (int j = 0; j < 16; ++j) acc = fmaf(u[j], Vc[j * 17 + i], acc);
    out[(size_t)mat * 256 + i * 16 + sub] = acc;
  }
}

// ---------------------------------------------------------------------------
extern "C" void kernel_launch(void* const* d_in, const int* in_sizes, int n_in,
                              void* d_out, int out_size, void* d_ws, size_t ws_size,
                              hipStream_t stream) {
  const float* S     = (const float*)d_in[0];
  const float* in_w  = (const float*)d_in[1];
  const float* in_b  = (const float*)d_in[2];
  const float* out_w = (const float*)d_in[3];
  const float* out_b = (const float*)d_in[4];
  float* out = (float*)d_out;
  float* ws = (float*)d_ws;
  // workspace (f32): vec_in[16384*136] | qkv[3][64][34][1024] | attn[16384*136] | vec_out[16384*136]
  float* vec_in  = ws;
  float* qkv     = vec_in + (size_t)NMAT * DIMV;
  float* attn    = qkv    + (size_t)NMAT * QKVD;
  float* vec_out = attn   + (size_t)NMAT * DIMV;

  k1_logvec <<<dim3(NMAT / 16),      dim3(256), 0, stream>>>(S, vec_in);
  k2_qkv    <<<dim3(NMAT / 256, 24), dim3(256), 0, stream>>>(vec_in, in_w, in_b, qkv);
  k3_attn   <<<dim3(64, 8),          dim3(256), 0, stream>>>(qkv, attn);
  k4_outproj<<<dim3(NMAT / 256, 8),  dim3(256), 0, stream>>>(attn, out_w, out_b, vec_in, vec_out);
  k5_expm   <<<dim3(NMAT / 16),      dim3(256), 0, stream>>>(vec_out, out);
}

// Round 7
// 658.191 us; speedup vs baseline: 3.5810x; 1.0193x over previous
//
#include <hip/hip_runtime.h>
#include <math.h>

#define B_SZ 16
#define L_SZ 1024
#define NMAT (B_SZ * L_SZ)   // 16384
#define DIMV 136
#define QKVD 408
#define HD 34
#define NH 4
#define NSWEEP 5

typedef __attribute__((ext_vector_type(8))) short short8;
typedef __attribute__((ext_vector_type(16))) float f32x16;
union F8 { short8 s; uint32_t u[4]; };

struct S3 { uint32_t h, m, l; };
// 3-way truncation split of f32 into bf16 parts (stored as f32 with low16=0).
__device__ __forceinline__ S3 split3(float x) {
  S3 r;
  uint32_t xb = __float_as_uint(x);
  r.h = xb & 0xffff0000u;
  float rr = x - __uint_as_float(r.h);
  r.m = __float_as_uint(rr) & 0xffff0000u;
  float r2 = rr - __uint_as_float(r.m);
  r.l = __float_as_uint(r2) & 0xffff0000u;
  return r;
}
__device__ __forceinline__ uint32_t pkb(uint32_t a, uint32_t b) { return (a >> 16) | b; }

// ---------------------------------------------------------------------------
// sel16: extract a[j] for runtime j via cndmask tree
// ---------------------------------------------------------------------------
__device__ __forceinline__ float sel16(const float a[16], int j) {
  float p0 = (j & 1) ? a[1] : a[0];
  float p1 = (j & 1) ? a[3] : a[2];
  float p2 = (j & 1) ? a[5] : a[4];
  float p3 = (j & 1) ? a[7] : a[6];
  float p4 = (j & 1) ? a[9] : a[8];
  float p5 = (j & 1) ? a[11] : a[10];
  float p6 = (j & 1) ? a[13] : a[12];
  float p7 = (j & 1) ? a[15] : a[14];
  float q0 = (j & 2) ? p1 : p0;
  float q1 = (j & 2) ? p3 : p2;
  float q2 = (j & 2) ? p5 : p4;
  float q3 = (j & 2) ? p7 : p6;
  float r0 = (j & 4) ? q1 : q0;
  float r1 = (j & 4) ? q3 : q2;
  return (j & 8) ? r1 : r0;
}

// ---------------------------------------------------------------------------
// ILP-2 register+shuffle parallel cyclic Jacobi: one 16-lane group solves TWO
// independent 16x16 symmetric matrices with interleaved instruction streams
// (matrix B's shuffles hide under matrix A's FMA chain and vice versa).
// Pairing/index math shared. c,s recomputed per-lane from broadcast t.
// ---------------------------------------------------------------------------
__device__ __forceinline__ void jacobi16x2(float a0[16], float v0[16], float& d0,
                                           float a1[16], float v1[16], float& d1,
                                           const int lane) {
  const int sub = lane & 15;
  const int gbase = lane & 48;
  for (int sweep = 0; sweep < NSWEEP; ++sweep) {
#pragma unroll
    for (int r = 0; r < 15; ++r) {
      int partner;
      if (sub == 15) partner = r;
      else {
        int d = sub - r; if (d < 0) d += 15;
        if (d == 0) partner = 15;
        else if (d <= 7) { partner = r - d; if (partner < 0) partner += 15; }
        else { partner = r + 15 - d; if (partner >= 15) partner -= 15; }
      }
      const int plane = gbase | partner;
      const bool amP = sub < partner;
      const int pl = gbase | (amP ? sub : partner);

      float oa0[16], oa1[16], ov0[16], ov1[16];
#pragma unroll
      for (int i = 0; i < 16; ++i) { oa0[i] = __shfl(a0[i], plane); oa1[i] = __shfl(a1[i], plane); }
#pragma unroll
      for (int i = 0; i < 16; ++i) { ov0[i] = __shfl(v0[i], plane); ov1[i] = __shfl(v1[i], plane); }
      const float dO0 = __shfl(d0, plane);
      const float dO1 = __shfl(d1, plane);
      const float apqL0 = sel16(a0, partner);
      const float apqL1 = sel16(a1, partner);
      const float apq0 = __shfl(apqL0, pl);
      const float apq1 = __shfl(apqL1, pl);
      const float app0 = amP ? d0 : dO0, aqq0 = amP ? dO0 : d0;
      const float app1 = amP ? d1 : dO1, aqq1 = amP ? dO1 : d1;

      float t0, c0, s0;
      {
        float th = (aqq0 - app0) / (2.f * apq0);
        float tt = 1.f / (fabsf(th) + sqrtf(fmaf(th, th, 1.f)));
        tt = (th < 0.f) ? -tt : tt;
        t0 = (fabsf(apq0) < 1e-30f) ? 0.f : tt;
        c0 = rsqrtf(fmaf(t0, t0, 1.f)); s0 = t0 * c0;
      }
      float t1, c1, s1;
      {
        float th = (aqq1 - app1) / (2.f * apq1);
        float tt = 1.f / (fabsf(th) + sqrtf(fmaf(th, th, 1.f)));
        tt = (th < 0.f) ? -tt : tt;
        t1 = (fabsf(apq1) < 1e-30f) ? 0.f : tt;
        c1 = rsqrtf(fmaf(t1, t1, 1.f)); s1 = t1 * c1;
      }
      const float sg0 = amP ? -s0 : s0;
      const float sg1 = amP ? -s1 : s1;
#pragma unroll
      for (int i = 0; i < 16; ++i) {
        a0[i] = fmaf(sg0, oa0[i], c0 * a0[i]);
        a1[i] = fmaf(sg1, oa1[i], c1 * a1[i]);
      }
#pragma unroll
      for (int i = 0; i < 16; ++i) {
        v0[i] = fmaf(sg0, ov0[i], c0 * v0[i]);
        v1[i] = fmaf(sg1, ov1[i], c1 * v1[i]);
      }
      {
        const float cc = c0*c0, ss = s0*s0, cs2 = 2.f*c0*s0;
        d0 = amP ? fmaf(cc, app0, fmaf(ss, aqq0, -cs2*apq0))
                 : fmaf(ss, app0, fmaf(cc, aqq0,  cs2*apq0));
      }
      {
        const float cc = c1*c1, ss = s1*s1, cs2 = 2.f*c1*s1;
        d1 = amP ? fmaf(cc, app1, fmaf(ss, aqq1, -cs2*apq1))
                 : fmaf(ss, app1, fmaf(cc, aqq1,  cs2*apq1));
      }
#pragma unroll
      for (int k = 0; k < 8; ++k) {
        const int owner = (k == 0) ? r : (r + k) % 15;
        const float tk0 = __shfl(t0, gbase | owner);
        const float tk1 = __shfl(t1, gbase | owner);
        const float ck0 = rsqrtf(fmaf(tk0, tk0, 1.f)), sk0 = tk0 * ck0;
        const float ck1 = rsqrtf(fmaf(tk1, tk1, 1.f)), sk1 = tk1 * ck1;
        int pk, qk;
        if (k == 0) { pk = r; qk = 15; }
        else {
          const int u = (r + k) % 15, w = (r + 15 - k) % 15;
          pk = u < w ? u : w; qk = u < w ? w : u;
        }
        float tp = a0[pk], tq = a0[qk];
        a0[pk] = fmaf(-sk0, tq, ck0 * tp);
        a0[qk] = fmaf( sk0, tp, ck0 * tq);
        tp = a1[pk]; tq = a1[qk];
        a1[pk] = fmaf(-sk1, tq, ck1 * tp);
        a1[qk] = fmaf( sk1, tp, ck1 * tq);
      }
    }
  }
}

// ---------------------------------------------------------------------------
// K1: log_eig(S) -> tril vector, DIM-MAJOR out: vec[136][16384]
// 32 matrices per block (2 per 16-lane group, ILP-2).
// ---------------------------------------------------------------------------
__global__ __launch_bounds__(256, 2) void k1_logvec(const float* __restrict__ S, float* __restrict__ vec) {
  __shared__ float Vld[32][272];
  __shared__ float lwld[32][16];
  const int tid = threadIdx.x;
  const int lane = tid & 63;
  const int mloc = tid >> 4;
  const int sub = tid & 15;
  const int matA = blockIdx.x * 32 + mloc;
  const int matB = matA + 16;
  float a0[16], v0[16], a1[16], v1[16], d0 = 0.f, d1 = 0.f;
  const float* SpA = S + (size_t)matA * 256;
  const float* SpB = S + (size_t)matB * 256;
#pragma unroll
  for (int i = 0; i < 16; ++i) {
    a0[i] = SpA[i * 16 + sub];
    a1[i] = SpB[i * 16 + sub];
    const float id = (i == sub) ? 1.f : 0.f;
    v0[i] = id; v1[i] = id;
    if (i == sub) { d0 = a0[i]; d1 = a1[i]; }
  }
  jacobi16x2(a0, v0, d0, a1, v1, d1, lane);
#pragma unroll
  for (int i = 0; i < 16; ++i) {
    Vld[mloc][sub * 17 + i] = v0[i];
    Vld[mloc + 16][sub * 17 + i] = v1[i];
  }
  lwld[mloc][sub]      = __logf(fmaxf(d0, 1e-8f));
  lwld[mloc + 16][sub] = __logf(fmaxf(d1, 1e-8f));
  __syncthreads();
#pragma unroll
  for (int m2 = 0; m2 < 2; ++m2) {
    const int ml = mloc + m2 * 16;
    const int mat = blockIdx.x * 32 + ml;
    const float* Vc = &Vld[ml][0];
    for (int idx = sub; idx < DIMV; idx += 16) {
      int rr = (int)((sqrtf(8.f * (float)idx + 1.f) - 1.f) * 0.5f);
      while ((rr + 1) * (rr + 2) / 2 <= idx) ++rr;
      while (rr * (rr + 1) / 2 > idx) --rr;
      const int ccol = idx - rr * (rr + 1) / 2;
      float acc = 0.f;
#pragma unroll
      for (int j = 0; j < 16; ++j)
        acc += lwld[ml][j] * Vc[j * 17 + rr] * Vc[j * 17 + ccol];
      vec[(size_t)idx * NMAT + mat] = acc;
    }
  }
}

// ---------------------------------------------------------------------------
// K2: QKV projection. X dim-major [136][16384] (coalesced float2 loads, 2
// rows/thread); W wave-uniform (scalar loads); out qkv [part][b*4+h][34][1024].
// ---------------------------------------------------------------------------
__global__ __launch_bounds__(256) void k2_qkv(const float* __restrict__ X, const float* __restrict__ W,
                                              const float* __restrict__ bias, float* __restrict__ Y) {
  const int r0 = blockIdx.x * 512 + threadIdx.x * 2;
  const int n0 = blockIdx.y * 17;
  float accx[17], accy[17];
#pragma unroll
  for (int c = 0; c < 17; ++c) { const float bv = bias[n0 + c]; accx[c] = bv; accy[c] = bv; }
  for (int k = 0; k < DIMV; ++k) {
    const float2 xv = *(const float2*)&X[(size_t)k * NMAT + r0];
#pragma unroll
    for (int c = 0; c < 17; ++c) {
      const float wv = W[(size_t)(n0 + c) * DIMV + k];
      accx[c] = fmaf(wv, xv.x, accx[c]);
      accy[c] = fmaf(wv, xv.y, accy[c]);
    }
  }
  const int b = r0 >> 10, lrow = r0 & 1023;
#pragma unroll
  for (int c = 0; c < 17; ++c) {
    const int n = n0 + c;
    const int p = n / DIMV, rr = n - p * DIMV;
    const int hh = rr / HD, dd = rr - hh * HD;
    *(float2*)&Y[(((size_t)(p * 64 + b * NH + hh)) * HD + dd) * L_SZ + lrow] =
        make_float2(accx[c], accy[c]);
  }
}

// ---------------------------------------------------------------------------
// K3: flash attention via split-bf16x3 MFMA (32x32x16).
// QKV dim-major [part][bh][dim][row]; output attn DIM-MAJOR [136][16384].
// ---------------------------------------------------------------------------
__global__ __launch_bounds__(256) void k3_attn(const float* __restrict__ QKV, float* __restrict__ Oout) {
  __shared__ __align__(16) uint32_t Kh[6 * 32 * 4], Km[6 * 32 * 4], Kl[6 * 32 * 4];
  __shared__ __align__(16) uint16_t VTh[4 * 64 * 8], VTm[4 * 64 * 8], VTl[4 * 64 * 8];
  const int tid = threadIdx.x;
  const int lane = tid & 63;
  const int w = tid >> 6;
  const int bh = blockIdx.x;
  const int head = bh & 3;
  const int b = bh >> 2;
  const int qrl = lane & 31;
  const int hh = lane >> 5;
  const int row = blockIdx.y * 128 + w * 32 + qrl;
  const float* __restrict__ Qp = QKV + ((size_t)(0 * 64 + bh)) * HD * L_SZ;
  const float* __restrict__ Kp = QKV + ((size_t)(1 * 64 + bh)) * HD * L_SZ;
  const float* __restrict__ Vp = QKV + ((size_t)(2 * 64 + bh)) * HD * L_SZ;
  const float scale = 0.1714985851425088f;  // 1/sqrt(34)

  for (int i = tid; i < 6 * 32 * 4; i += 256) { Kh[i] = 0; Km[i] = 0; Kl[i] = 0; }
  for (int i = tid; i < 4 * 64 * 8; i += 256) { VTh[i] = 0; VTm[i] = 0; VTl[i] = 0; }

  F8 qfh[3], qfm[3], qfl[3];
#pragma unroll
  for (int c = 0; c < 3; ++c) {
#pragma unroll
    for (int e2 = 0; e2 < 4; ++e2) {
      const int kd = c * 16 + hh * 8 + 2 * e2;
      float x = 0.f, y = 0.f;
      if (kd < HD) {
        x = Qp[(size_t)kd * L_SZ + row] * scale;
        y = Qp[(size_t)(kd + 1) * L_SZ + row] * scale;
      }
      S3 sx = split3(x), sy = split3(y);
      qfh[c].u[e2] = pkb(sx.h, sy.h);
      qfm[c].u[e2] = pkb(sx.m, sy.m);
      qfl[c].u[e2] = pkb(sx.l, sy.l);
    }
  }

  f32x16 o0, o1;
#pragma unroll
  for (int i = 0; i < 16; ++i) { o0[i] = 0.f; o1[i] = 0.f; }
  float mrun = -3.0e38f, lsum = 0.f;

  for (int t = 0; t < 32; ++t) {
    __syncthreads();
    for (int u = tid; u < 1088; u += 256) {
      const bool isK = u < 544;
      const int e = isK ? u : u - 544;
      const int key = e & 31;
      const int j = e >> 5;
      const float* __restrict__ P = isK ? Kp : Vp;
      const size_t base = (size_t)(t * 32 + key);
      const float x = P[(size_t)(2 * j) * L_SZ + base];
      const float y = P[(size_t)(2 * j + 1) * L_SZ + base];
      const S3 sx = split3(x), sy = split3(y);
      if (isK) {
        const int di = ((j >> 2) * 32 + key) * 4 + (j & 3);
        Kh[di] = pkb(sx.h, sy.h); Km[di] = pkb(sx.m, sy.m); Kl[di] = pkb(sx.l, sy.l);
      } else {
        const int b0 = ((key >> 3) * 64 + 2 * j) * 8 + (key & 7);
        VTh[b0] = (uint16_t)(sx.h >> 16); VTm[b0] = (uint16_t)(sx.m >> 16); VTl[b0] = (uint16_t)(sx.l >> 16);
        VTh[b0 + 8] = (uint16_t)(sy.h >> 16); VTm[b0 + 8] = (uint16_t)(sy.m >> 16); VTl[b0 + 8] = (uint16_t)(sy.l >> 16);
      }
    }
    __syncthreads();

    f32x16 s;
#pragma unroll
    for (int i = 0; i < 16; ++i) s[i] = 0.f;
#pragma unroll
    for (int c = 0; c < 3; ++c) {
      F8 ah, am, al;
      const int kidx = ((c * 2 + hh) * 32 + qrl) * 4;
      ah.s = *(const short8*)&Kh[kidx];
      am.s = *(const short8*)&Km[kidx];
      al.s = *(const short8*)&Kl[kidx];
      s = __builtin_amdgcn_mfma_f32_32x32x16_bf16(ah.s, qfh[c].s, s, 0, 0, 0);
      s = __builtin_amdgcn_mfma_f32_32x32x16_bf16(ah.s, qfm[c].s, s, 0, 0, 0);
      s = __builtin_amdgcn_mfma_f32_32x32x16_bf16(am.s, qfh[c].s, s, 0, 0, 0);
      s = __builtin_amdgcn_mfma_f32_32x32x16_bf16(ah.s, qfl[c].s, s, 0, 0, 0);
      s = __builtin_amdgcn_mfma_f32_32x32x16_bf16(am.s, qfm[c].s, s, 0, 0, 0);
      s = __builtin_amdgcn_mfma_f32_32x32x16_bf16(al.s, qfh[c].s, s, 0, 0, 0);
    }

    float mymax = s[0];
#pragma unroll
    for (int e = 1; e < 16; ++e) mymax = fmaxf(mymax, s[e]);
    const float pmax = fmaxf(mymax, __shfl_xor(mymax, 32));
    const float mn = fmaxf(mrun, pmax);
    const float corr = __expf(mrun - mn);
    mrun = mn;
    float p[16]; float ps = 0.f;
#pragma unroll
    for (int e = 0; e < 16; ++e) { p[e] = __expf(s[e] - mn); ps += p[e]; }
    ps += __shfl_xor(ps, 32);
    lsum = lsum * corr + ps;
    o0 *= corr; o1 *= corr;

    uint32_t uo[3][8], po[3][8];
#pragma unroll
    for (int g = 0; g < 8; ++g) {
      const S3 s0 = split3(p[2 * g]), s1 = split3(p[2 * g + 1]);
      uo[0][g] = pkb(s0.h, s1.h); uo[1][g] = pkb(s0.m, s1.m); uo[2][g] = pkb(s0.l, s1.l);
    }
#pragma unroll
    for (int sp = 0; sp < 3; ++sp)
#pragma unroll
      for (int g = 0; g < 8; ++g) po[sp][g] = (uint32_t)__shfl_xor((int)uo[sp][g], 32);
    F8 pf[3][2];
#pragma unroll
    for (int sp = 0; sp < 3; ++sp) {
      pf[sp][0].u[0] = hh ? po[sp][2] : uo[sp][0];
      pf[sp][0].u[1] = hh ? po[sp][3] : uo[sp][1];
      pf[sp][0].u[2] = hh ? uo[sp][2] : po[sp][0];
      pf[sp][0].u[3] = hh ? uo[sp][3] : po[sp][1];
      pf[sp][1].u[0] = hh ? po[sp][6] : uo[sp][4];
      pf[sp][1].u[1] = hh ? po[sp][7] : uo[sp][5];
      pf[sp][1].u[2] = hh ? uo[sp][6] : po[sp][4];
      pf[sp][1].u[3] = hh ? uo[sp][7] : po[sp][5];
    }

#pragma unroll
    for (int dt = 0; dt < 2; ++dt) {
#pragma unroll
      for (int kc = 0; kc < 2; ++kc) {
        const int vb = ((kc * 2 + hh) * 64 + dt * 32 + qrl) * 8;
        F8 vh2, vm2, vl2;
        vh2.s = *(const short8*)&VTh[vb];
        vm2.s = *(const short8*)&VTm[vb];
        vl2.s = *(const short8*)&VTl[vb];
        f32x16 oa = dt ? o1 : o0;
        oa = __builtin_amdgcn_mfma_f32_32x32x16_bf16(vh2.s, pf[0][kc].s, oa, 0, 0, 0);
        oa = __builtin_amdgcn_mfma_f32_32x32x16_bf16(vh2.s, pf[1][kc].s, oa, 0, 0, 0);
        oa = __builtin_amdgcn_mfma_f32_32x32x16_bf16(vm2.s, pf[0][kc].s, oa, 0, 0, 0);
        oa = __builtin_amdgcn_mfma_f32_32x32x16_bf16(vh2.s, pf[2][kc].s, oa, 0, 0, 0);
        oa = __builtin_amdgcn_mfma_f32_32x32x16_bf16(vm2.s, pf[1][kc].s, oa, 0, 0, 0);
        oa = __builtin_amdgcn_mfma_f32_32x32x16_bf16(vl2.s, pf[0][kc].s, oa, 0, 0, 0);
        if (dt) o1 = oa; else o0 = oa;
      }
    }
  }

  // ---- epilogue: dim-major coalesced stores attn[head*34+d][16384] ----
  const float inv = 1.f / lsum;
  const int rowG = b * L_SZ + row;
#pragma unroll
  for (int dt = 0; dt < 2; ++dt) {
#pragma unroll
    for (int rq = 0; rq < 4; ++rq) {
#pragma unroll
      for (int j = 0; j < 4; ++j) {
        const int d = dt * 32 + 8 * rq + 4 * hh + j;
        if (d < HD) {
          const float val = (dt ? o1[rq * 4 + j] : o0[rq * 4 + j]) * inv;
          Oout[(size_t)(head * HD + d) * NMAT + rowG] = val;
        }
      }
    }
  }
}

// ---------------------------------------------------------------------------
// K4: out-projection + residual. X=attn dim-major, resid=vec_in dim-major,
// out vec_out dim-major [136][16384]. 2 rows/thread, coalesced.
// ---------------------------------------------------------------------------
__global__ __launch_bounds__(256) void k4_outproj(const float* __restrict__ X, const float* __restrict__ W,
                                                  const float* __restrict__ bias, const float* __restrict__ resid,
                                                  float* __restrict__ Y) {
  const int r0 = blockIdx.x * 512 + threadIdx.x * 2;
  const int n0 = blockIdx.y * 17;
  float accx[17], accy[17];
#pragma unroll
  for (int c = 0; c < 17; ++c) { const float bv = bias[n0 + c]; accx[c] = bv; accy[c] = bv; }
  for (int k = 0; k < DIMV; ++k) {
    const float2 xv = *(const float2*)&X[(size_t)k * NMAT + r0];
#pragma unroll
    for (int c = 0; c < 17; ++c) {
      const float wv = W[(size_t)(n0 + c) * DIMV + k];
      accx[c] = fmaf(wv, xv.x, accx[c]);
      accy[c] = fmaf(wv, xv.y, accy[c]);
    }
  }
#pragma unroll
  for (int c = 0; c < 17; ++c) {
    const float2 rv = *(const float2*)&resid[(size_t)(n0 + c) * NMAT + r0];
    *(float2*)&Y[(size_t)(n0 + c) * NMAT + r0] = make_float2(accx[c] + rv.x, accy[c] + rv.y);
  }
}

// ---------------------------------------------------------------------------
// K5: rebuild symmetric matrix from vec_out (dim-major), exp_eig, write
// 16x16 output. ILP-2: 32 matrices per block.
// ---------------------------------------------------------------------------
__global__ __launch_bounds__(256, 2) void k5_expm(const float* __restrict__ vecOut, float* __restrict__ out) {
  __shared__ float Vld[32][272];
  __shared__ float eld[32][16];
  const int tid = threadIdx.x;
  const int lane = tid & 63;
  const int mloc = tid >> 4;
  const int sub = tid & 15;
  const int matA = blockIdx.x * 32 + mloc;
  const int matB = matA + 16;
  float a0[16], v0[16], a1[16], v1[16], d0 = 0.f, d1 = 0.f;
#pragma unroll
  for (int i = 0; i < 16; ++i) {
    const int rr = i > sub ? i : sub;
    const int cc = i + sub - rr;
    const size_t off = (size_t)(rr * (rr + 1) / 2 + cc) * NMAT;
    a0[i] = vecOut[off + matA];
    a1[i] = vecOut[off + matB];
    const float id = (i == sub) ? 1.f : 0.f;
    v0[i] = id; v1[i] = id;
    if (i == sub) { d0 = a0[i]; d1 = a1[i]; }
  }
  jacobi16x2(a0, v0, d0, a1, v1, d1, lane);
#pragma unroll
  for (int i = 0; i < 16; ++i) {
    Vld[mloc][sub * 17 + i] = v0[i];
    Vld[mloc + 16][sub * 17 + i] = v1[i];
  }
  eld[mloc][sub]      = __expf(d0);
  eld[mloc + 16][sub] = __expf(d1);
  __syncthreads();
#pragma unroll
  for (int m2 = 0; m2 < 2; ++m2) {
    const int ml = mloc + m2 * 16;
    const int mat = blockIdx.x * 32 + ml;
    const float* Vc = &Vld[ml][0];
    float u[16];
#pragma unroll
    for (int j = 0; j < 16; ++j) u[j] = eld[ml][j] * Vc[j * 17 + sub];
#pragma unroll
    for (int i = 0; i < 16; ++i) {
      float acc = 0.f;
#pragma unroll
      for (int j = 0; j < 16; ++j) acc = fmaf(u[j], Vc[j * 17 + i], acc);
      out[(size_t)mat * 256 + i * 16 + sub] = acc;
    }
  }
}

// ---------------------------------------------------------------------------
extern "C" void kernel_launch(void* const* d_in, const int* in_sizes, int n_in,
                              void* d_out, int out_size, void* d_ws, size_t ws_size,
                              hipStream_t stream) {
  const float* S     = (const float*)d_in[0];
  const float* in_w  = (const float*)d_in[1];
  const float* in_b  = (const float*)d_in[2];
  const float* out_w = (const float*)d_in[3];
  const float* out_b = (const float*)d_in[4];
  float* out = (float*)d_out;
  float* ws = (float*)d_ws;
  // workspace (f32), all activations dim-major:
  // vec_in[136][16384] | qkv[3][64][34][1024] | attn[136][16384] | vec_out[136][16384]
  float* vec_in  = ws;
  float* qkv     = vec_in + (size_t)NMAT * DIMV;
  float* attn    = qkv    + (size_t)NMAT * QKVD;
  float* vec_out = attn   + (size_t)NMAT * DIMV;

  k1_logvec <<<dim3(NMAT / 32),     dim3(256), 0, stream>>>(S, vec_in);
  k2_qkv    <<<dim3(NMAT / 512, 24), dim3(256), 0, stream>>>(vec_in, in_w, in_b, qkv);
  k3_attn   <<<dim3(64, 8),          dim3(256), 0, stream>>>(qkv, attn);
  k4_outproj<<<dim3(NMAT / 512, 8),  dim3(256), 0, stream>>>(attn, out_w, out_b, vec_in, vec_out);
  k5_expm   <<<dim3(NMAT / 32),      dim3(256), 0, stream>>>(vec_out, out);
}